// Round 6
// baseline (14789.494 us; speedup 1.0000x reference)
//
#include <hip/hip_runtime.h>
#include <math.h>

#define NV      50000
#define T_STEPS 1023
#define KDIM    1024
#define NCH     782   // ceil(50000/64)
typedef unsigned long long ull;

// ws layout (bytes):
//   [0, 4)               cnt   (grid-barrier counter, re-zeroed each launch)
//   [8192, 12288)        Psum  f32[1024]
//   [12288, 16384)       Ttgt  f32[1024]
//   [24K, 24K+4M)        X     f32[1024*1024]
//   [24K+4M, 24K+28M)    GI    f64[1024*3072]; after recurrence:
//                          [+0, +8M)       E f64[1024*1024]
//                          [+8M, +14.5M)   candL f32[1024*1564]
//                          [+14.5M,+21M)   candI i32[1024*1564]
//   [24K+28M, 24K+36M)   H     f64[1024*1024]
// total ~36.02 MiB

// ---------------------------------------------------------------- gather ----
__global__ __launch_bounds__(256) void k_gather(const int* __restrict__ inputs,
                                                const float* __restrict__ emb,
                                                float* __restrict__ X) {
  const int t = blockIdx.x;      // 0..1023 (row 1023 = zero pad)
  const int tid = threadIdx.x;
  float4 v = make_float4(0.f, 0.f, 0.f, 0.f);
  if (t < T_STEPS) {
    const int tok = (t == 0) ? 0 : inputs[t];
    v = *(const float4*)&emb[(size_t)tok * KDIM + tid * 4];
  }
  *(float4*)&X[(size_t)t * KDIM + tid * 4] = v;
}

// ---------------- NT GEMM: A f32 x B f32 -> C f64, fp64 accumulate ----------
__global__ __launch_bounds__(256) void k_gemm_ffd(const float* __restrict__ A,
                                                  const float* __restrict__ B,
                                                  const float* __restrict__ bias,
                                                  double* __restrict__ C,
                                                  int N, int K) {
  __shared__ float As[32][68];
  __shared__ float Bs[32][68];
  const int tid = threadIdx.x;
  const int bx = blockIdx.x, by = blockIdx.y;
  const int lr = tid >> 2;            // 0..63
  const int lk = (tid & 3) * 8;       // 0,8,16,24
  const float* Ap = A + (size_t)(by * 64 + lr) * K + lk;
  const float* Bp = B + (size_t)(bx * 64 + lr) * K + lk;
  const int r0 = (tid >> 4) * 4;
  const int c0 = (tid & 15) * 4;
  double acc[4][4] = {};
  for (int kc = 0; kc < K; kc += 32) {
    const float4 a0 = *(const float4*)(Ap + kc);
    const float4 a1 = *(const float4*)(Ap + kc + 4);
    const float4 b0 = *(const float4*)(Bp + kc);
    const float4 b1 = *(const float4*)(Bp + kc + 4);
    __syncthreads();
    As[lk+0][lr]=a0.x; As[lk+1][lr]=a0.y; As[lk+2][lr]=a0.z; As[lk+3][lr]=a0.w;
    As[lk+4][lr]=a1.x; As[lk+5][lr]=a1.y; As[lk+6][lr]=a1.z; As[lk+7][lr]=a1.w;
    Bs[lk+0][lr]=b0.x; Bs[lk+1][lr]=b0.y; Bs[lk+2][lr]=b0.z; Bs[lk+3][lr]=b0.w;
    Bs[lk+4][lr]=b1.x; Bs[lk+5][lr]=b1.y; Bs[lk+6][lr]=b1.z; Bs[lk+7][lr]=b1.w;
    __syncthreads();
#pragma unroll
    for (int kk = 0; kk < 32; ++kk) {
      const float4 av = *(const float4*)&As[kk][r0];
      const float4 bv = *(const float4*)&Bs[kk][c0];
      const double aa[4] = {av.x, av.y, av.z, av.w};
      const double bb[4] = {bv.x, bv.y, bv.z, bv.w};
#pragma unroll
      for (int i = 0; i < 4; ++i)
#pragma unroll
        for (int j = 0; j < 4; ++j)
          acc[i][j] = fma(aa[i], bb[j], acc[i][j]);
    }
  }
  const int row = by * 64 + r0;
  const int col = bx * 64 + c0;
#pragma unroll
  for (int i = 0; i < 4; ++i)
#pragma unroll
    for (int j = 0; j < 4; ++j)
      C[(size_t)(row + i) * N + col + j] = acc[i][j] + (double)bias[col + j];
}

// ---------------- NT GEMM: A f64 x B f32 -> C f64, fp64 accumulate ----------
__global__ __launch_bounds__(256) void k_gemm_dfd(const double* __restrict__ A,
                                                  const float* __restrict__ B,
                                                  const float* __restrict__ bias,
                                                  double* __restrict__ C,
                                                  int N, int K) {
  __shared__ double As[32][68];
  __shared__ float  Bs[32][68];
  const int tid = threadIdx.x;
  const int bx = blockIdx.x, by = blockIdx.y;
  const int lr = tid >> 2;
  const int lk = (tid & 3) * 8;
  const double* Ap = A + (size_t)(by * 64 + lr) * K + lk;
  const float*  Bp = B + (size_t)(bx * 64 + lr) * K + lk;
  const int r0 = (tid >> 4) * 4;
  const int c0 = (tid & 15) * 4;
  double acc[4][4] = {};
  for (int kc = 0; kc < K; kc += 32) {
    double ar[8];
#pragma unroll
    for (int q = 0; q < 8; ++q) ar[q] = Ap[kc + q];
    const float4 b0 = *(const float4*)(Bp + kc);
    const float4 b1 = *(const float4*)(Bp + kc + 4);
    __syncthreads();
#pragma unroll
    for (int q = 0; q < 8; ++q) As[lk + q][lr] = ar[q];
    Bs[lk+0][lr]=b0.x; Bs[lk+1][lr]=b0.y; Bs[lk+2][lr]=b0.z; Bs[lk+3][lr]=b0.w;
    Bs[lk+4][lr]=b1.x; Bs[lk+5][lr]=b1.y; Bs[lk+6][lr]=b1.z; Bs[lk+7][lr]=b1.w;
    __syncthreads();
#pragma unroll
    for (int kk = 0; kk < 32; ++kk) {
      const double aa[4] = {As[kk][r0+0], As[kk][r0+1], As[kk][r0+2], As[kk][r0+3]};
      const float4 bv = *(const float4*)&Bs[kk][c0];
      const double bb[4] = {bv.x, bv.y, bv.z, bv.w};
#pragma unroll
      for (int i = 0; i < 4; ++i)
#pragma unroll
        for (int j = 0; j < 4; ++j)
          acc[i][j] = fma(aa[i], bb[j], acc[i][j]);
    }
  }
  const int row = by * 64 + r0;
  const int col = bx * 64 + c0;
#pragma unroll
  for (int i = 0; i < 4; ++i)
#pragma unroll
    for (int j = 0; j < 4; ++j)
      C[(size_t)(row + i) * N + col + j] = acc[i][j] + (double)bias[col + j];
}

// -------------------- persistent GRU recurrence (single launch) -------------
// 64 blocks x 512 threads = 512 waves. Wave w of block b owns h-indices
// {b*16 + w*2, b*16 + w*2 + 1}; W_hh rows live in registers (fp32, 96 VGPR).
// Numerics identical to round-5's k_step (fp64 dots + gates).
// Cross-block protocol: agent-scope atomic H stores -> __syncthreads
// (drains vmcnt) -> tid0: release fence + atomicAdd(cnt) -> acquire spin.
__global__ __launch_bounds__(512, 2) void k_recur(const float* __restrict__ z,
                                                  const float* __restrict__ Whh,
                                                  const float* __restrict__ bhh,
                                                  const double* __restrict__ GI,
                                                  double* H, int* cnt) {
  __shared__ double hs[1024];
  const int tid = threadIdx.x;
  const int w = tid >> 6, l = tid & 63;
  const int ibase = blockIdx.x * 16 + w * 2;
  float wreg[6][16];
#pragma unroll
  for (int il = 0; il < 2; ++il)
#pragma unroll
    for (int g = 0; g < 3; ++g) {
      const float* wp = Whh + (size_t)(g * 1024 + ibase + il) * 1024 + l;
#pragma unroll
      for (int m = 0; m < 16; ++m) wreg[il * 3 + g][m] = wp[m * 64];
    }
  double bh[6];
#pragma unroll
  for (int il = 0; il < 2; ++il)
#pragma unroll
    for (int g = 0; g < 3; ++g) bh[il * 3 + g] = (double)bhh[g * 1024 + ibase + il];

  for (int t = 0; t < T_STEPS; ++t) {
    if (t == 0) {
      hs[tid]       = (double)z[tid];
      hs[tid + 512] = (double)z[tid + 512];
    } else {
      const double* hp = H + (size_t)(t - 1) * 1024;
      hs[tid]       = __hip_atomic_load(hp + tid,
                        __ATOMIC_RELAXED, __HIP_MEMORY_SCOPE_AGENT);
      hs[tid + 512] = __hip_atomic_load(hp + tid + 512,
                        __ATOMIC_RELAXED, __HIP_MEMORY_SCOPE_AGENT);
    }
    __syncthreads();
    double gi[6];
    {
      const double* gp = GI + (size_t)t * 3072;
#pragma unroll
      for (int il = 0; il < 2; ++il)
#pragma unroll
        for (int g = 0; g < 3; ++g) gi[il * 3 + g] = gp[g * 1024 + ibase + il];
    }
    double s[6] = {0.0, 0.0, 0.0, 0.0, 0.0, 0.0};
#pragma unroll
    for (int m = 0; m < 16; ++m) {
      const double hv = hs[l + 64 * m];
#pragma unroll
      for (int rr = 0; rr < 6; ++rr) s[rr] = fma((double)wreg[rr][m], hv, s[rr]);
    }
#pragma unroll
    for (int rr = 0; rr < 6; ++rr) {
      double v = s[rr];
#pragma unroll
      for (int mk = 32; mk >= 1; mk >>= 1) v += __shfl_xor(v, mk, 64);
      s[rr] = v;
    }
    if (l < 2) {                 // lane 0 -> il=0, lane 1 -> il=1
      const int il = l;
      const double r  = 1.0 / (1.0 + exp(-(gi[il * 3 + 0] + s[il * 3 + 0] + bh[il * 3 + 0])));
      const double zg = 1.0 / (1.0 + exp(-(gi[il * 3 + 1] + s[il * 3 + 1] + bh[il * 3 + 1])));
      const double n  = tanh(gi[il * 3 + 2] + r * (s[il * 3 + 2] + bh[il * 3 + 2]));
      const int gidx = ibase + il;
      const double hn = (1.0 - zg) * n + zg * hs[gidx];
      __hip_atomic_store(H + (size_t)t * 1024 + gidx, hn,
                         __ATOMIC_RELAXED, __HIP_MEMORY_SCOPE_AGENT);
    }
    __syncthreads();             // all stores in this block drained (vmcnt 0)
    if (tid == 0) {
      __hip_atomic_fetch_add(cnt, 1, __ATOMIC_RELEASE, __HIP_MEMORY_SCOPE_AGENT);
      const int target = (t + 1) * 64;
      while (__hip_atomic_load(cnt, __ATOMIC_ACQUIRE, __HIP_MEMORY_SCOPE_AGENT) < target)
        __builtin_amdgcn_s_sleep(1);
    }
    __syncthreads();
  }
}

// ------- logits GEMM (f64) + per-chunk fp32 top-2 candidates + loss stats ---
__global__ __launch_bounds__(256) void k_logits(const double* __restrict__ E,
                                                const float* __restrict__ emb,
                                                const float* __restrict__ out_b,
                                                const int* __restrict__ inputs,
                                                float* __restrict__ candL,
                                                int* __restrict__ candI,
                                                float* __restrict__ Psum,
                                                float* __restrict__ Ttgt) {
  __shared__ double As[32][68];
  __shared__ float  Bs[32][68];
  const int tid = threadIdx.x;
  const int bx = blockIdx.x, by = blockIdx.y;
  const int lr = tid >> 2;
  const int lk = (tid & 3) * 8;
  const int brow = bx * 64 + lr;
  const double* Ap = E + (size_t)(by * 64 + lr) * KDIM + lk;
  const float*  Bp = emb + (size_t)brow * KDIM + lk;
  const bool bvalid = (brow < NV);
  const int r0 = (tid >> 4) * 4;
  const int c0 = (tid & 15) * 4;
  double acc[4][4] = {};
  for (int kc = 0; kc < KDIM; kc += 32) {
    double ar[8];
#pragma unroll
    for (int q = 0; q < 8; ++q) ar[q] = Ap[kc + q];
    float4 b0 = make_float4(0.f, 0.f, 0.f, 0.f);
    float4 b1 = make_float4(0.f, 0.f, 0.f, 0.f);
    if (bvalid) { b0 = *(const float4*)(Bp + kc); b1 = *(const float4*)(Bp + kc + 4); }
    __syncthreads();
#pragma unroll
    for (int q = 0; q < 8; ++q) As[lk + q][lr] = ar[q];
    Bs[lk+0][lr]=b0.x; Bs[lk+1][lr]=b0.y; Bs[lk+2][lr]=b0.z; Bs[lk+3][lr]=b0.w;
    Bs[lk+4][lr]=b1.x; Bs[lk+5][lr]=b1.y; Bs[lk+6][lr]=b1.z; Bs[lk+7][lr]=b1.w;
    __syncthreads();
#pragma unroll
    for (int kk = 0; kk < 32; ++kk) {
      const double aa[4] = {As[kk][r0+0], As[kk][r0+1], As[kk][r0+2], As[kk][r0+3]};
      const float4 bv = *(const float4*)&Bs[kk][c0];
      const double bb[4] = {bv.x, bv.y, bv.z, bv.w};
#pragma unroll
      for (int i = 0; i < 4; ++i)
#pragma unroll
        for (int j = 0; j < 4; ++j)
          acc[i][j] = fma(aa[i], bb[j], acc[i][j]);
    }
  }
  const int colb = bx * 64 + c0;
#pragma unroll
  for (int i = 0; i < 4; ++i) {
    const int s = by * 64 + r0 + i;
    const bool valid = (s < T_STEPS);
    const int tgt = valid ? inputs[s + 1] : -1;
    float L1 = -3e38f, L2 = -3e38f;
    int   i1 = 0x7FFFFFFF, i2 = 0x7FFFFFFF;
    float se = 0.f, tv = -INFINITY;
#pragma unroll
    for (int j = 0; j < 4; ++j) {
      const int v = colb + j;
      if (v < NV) {
        const double lgd = acc[i][j] + (double)out_b[v];
        const float L = (float)lgd;           // np's fp32 logit (bit-matched)
        se += expf((float)(lgd - 0.01));
        if (v == tgt) tv = (float)lgd;
        if (L > L1 || (L == L1 && v < i1)) { L2 = L1; i2 = i1; L1 = L; i1 = v; }
        else if (L > L2 || (L == L2 && v < i2)) { L2 = L; i2 = v; }
      }
    }
#pragma unroll
    for (int mk = 1; mk <= 8; mk <<= 1) {
      const float oL1 = __shfl_xor(L1, mk, 64); const int oi1 = __shfl_xor(i1, mk, 64);
      const float oL2 = __shfl_xor(L2, mk, 64); const int oi2 = __shfl_xor(i2, mk, 64);
      if (oL1 > L1 || (oL1 == L1 && oi1 < i1)) { L2 = L1; i2 = i1; L1 = oL1; i1 = oi1; }
      else if (oL1 > L2 || (oL1 == L2 && oi1 < i2)) { L2 = oL1; i2 = oi1; }
      if (oL2 > L1 || (oL2 == L1 && oi2 < i1)) { L2 = L1; i2 = i1; L1 = oL2; i1 = oi2; }
      else if (oL2 > L2 || (oL2 == L2 && oi2 < i2)) { L2 = oL2; i2 = oi2; }
      se += __shfl_xor(se, mk, 64);
      tv = fmaxf(tv, __shfl_xor(tv, mk, 64));
    }
    if (((tid & 15) == 0) && valid) {
      const size_t p = (size_t)s * (2 * NCH) + 2 * bx;
      candL[p] = L1;     candI[p] = i1;
      candL[p + 1] = L2; candI[p + 1] = i2;
      atomicAdd(&Psum[s], se);
      if (tv > -1e30f) Ttgt[s] = tv;
    }
  }
}

// --------- preds: np-faithful fp32 log_softmax quantized argmax -------------
__global__ __launch_bounds__(256) void k_preds(const float* __restrict__ candL,
                                               const int* __restrict__ candI,
                                               float* __restrict__ out) {
  __shared__ float sL[256];
  __shared__ int   sI[256];
  const int s = blockIdx.x;        // 0..1022
  const int tid = threadIdx.x;
  const int n = 2 * NCH;           // 1564
  const size_t base = (size_t)s * n;
  float m = -3e38f;
  for (int c = tid; c < n; c += 256) m = fmaxf(m, candL[base + c]);
  sL[tid] = m; __syncthreads();
  for (int st = 128; st > 0; st >>= 1) {
    if (tid < st) sL[tid] = fmaxf(sL[tid], sL[tid + st]);
    __syncthreads();
  }
  const float Lmax = sL[0];
  __syncthreads();
  float bq = -3e38f; int bi = 0x7FFFFFFF;
  for (int c = tid; c < n; c += 256) {
    const float L = candL[base + c];
    const int   v = candI[base + c];
    const float d = L - Lmax;              // Sterbenz-exact
    const float q = d - 10.8125f;          // fp32 bucket quantization
    if (q > bq || (q == bq && v < bi)) { bq = q; bi = v; }
  }
  sL[tid] = bq; sI[tid] = bi; __syncthreads();
  for (int st = 128; st > 0; st >>= 1) {
    if (tid < st) {
      if (sL[tid + st] > sL[tid] ||
          (sL[tid + st] == sL[tid] && sI[tid + st] < sI[tid])) {
        sL[tid] = sL[tid + st]; sI[tid] = sI[tid + st];
      }
    }
    __syncthreads();
  }
  if (tid == 0) out[2 + s] = (float)sI[0];
}

// ------------------------------------------------ final loss ----------------
__global__ __launch_bounds__(1024) void k_finish(const float* __restrict__ Psum,
                                                 const float* __restrict__ Ttgt,
                                                 float* __restrict__ out) {
  __shared__ double red[1024];
  const int s = threadIdx.x;
  double ls = 0.0;
  if (s < T_STEPS) ls = 0.01 + log((double)Psum[s]) - (double)Ttgt[s];
  red[s] = ls;
  __syncthreads();
  for (int st = 512; st > 0; st >>= 1) {
    if (s < st) red[s] += red[s + st];
    __syncthreads();
  }
  if (s == 0) out[0] = (float)red[0];
  if (s == 1) out[1] = 0.f;
}

// ----------------------------------------------------------------- launch ---
extern "C" void kernel_launch(void* const* d_in, const int* in_sizes, int n_in,
                              void* d_out, int out_size, void* d_ws, size_t ws_size,
                              hipStream_t stream) {
  const int*   inputs = (const int*)  d_in[0];
  const float* z      = (const float*)d_in[1];
  const float* emb    = (const float*)d_in[2];
  const float* out_b  = (const float*)d_in[3];
  const float* h2eW   = (const float*)d_in[4];
  const float* h2eb   = (const float*)d_in[5];
  const float* Wih    = (const float*)d_in[6];
  const float* Whh    = (const float*)d_in[7];
  const float* bih    = (const float*)d_in[8];
  const float* bhh    = (const float*)d_in[9];

  char* ws8 = (char*)d_ws;
  int*    cnt  = (int*)ws8;                              // [0,4)
  float*  Psum = (float*)(ws8 + 8192);                   // 4 KiB
  float*  Ttgt = (float*)(ws8 + 12288);                  // 4 KiB
  float*  X    = (float*)(ws8 + 24576);                  // 4 MiB
  char*   GIb  = ws8 + 24576 + (4u << 20);               // 24 MiB region
  double* GI   = (double*)GIb;
  double* E    = GI;                                     // 8 MiB overlay
  float*  candL = (float*)(GIb + (8u << 20));            // 6.11 MiB
  int*    candI = (int*)  (GIb + (8u << 20) + 6815744);  // 6.11 MiB
  double* H    = (double*)(ws8 + 24576 + (28u << 20));   // 8 MiB
  float*  out  = (float*)d_out;

  hipMemsetAsync(ws8, 0, 16384, stream);                 // cnt + Psum + Ttgt

  k_gather<<<1024, 256, 0, stream>>>(inputs, emb, X);
  k_gemm_ffd<<<dim3(48, 16), 256, 0, stream>>>(X, Wih, bih, GI, 3072, KDIM);
  k_recur<<<64, 512, 0, stream>>>(z, Whh, bhh, GI, H, cnt);
  k_gemm_dfd<<<dim3(16, 16), 256, 0, stream>>>(H, h2eW, h2eb, E, KDIM, KDIM);
  k_logits<<<dim3(NCH, 16), 256, 0, stream>>>(E, emb, out_b, inputs,
                                              candL, candI, Psum, Ttgt);
  k_preds<<<T_STEPS, 256, 0, stream>>>(candL, candI, out);
  k_finish<<<1, 1024, 0, stream>>>(Psum, Ttgt, out);
}

// Round 7
// 12315.170 us; speedup vs baseline: 1.2009x; 1.2009x over previous
//
#include <hip/hip_runtime.h>
#include <math.h>

#define NV      50000
#define T_STEPS 1023
#define KDIM    1024
#define NCH     782   // ceil(50000/64)
typedef unsigned long long ull;

// ws layout (bytes):
//   [0, 8192)            flags int[2][64] at 64B stride (grid barrier)
//   [8192, 12288)        Psum  f32[1024]
//   [12288, 16384)       Ttgt  f32[1024]
//   [24K, 24K+4M)        X     f32[1024*1024]
//   [24K+4M, 24K+28M)    GI    f64[1024*3072]; after recurrence:
//                          [+0, +8M)       E f64[1024*1024]
//                          [+8M, +14.5M)   candL f32[1024*1564]
//                          [+14.5M,+21M)   candI i32[1024*1564]
//   [24K+28M, 24K+36M)   H     f64[1024*1024]
// total ~36.02 MiB

// ---------------------------------------------------------------- gather ----
__global__ __launch_bounds__(256) void k_gather(const int* __restrict__ inputs,
                                                const float* __restrict__ emb,
                                                float* __restrict__ X) {
  const int t = blockIdx.x;      // 0..1023 (row 1023 = zero pad)
  const int tid = threadIdx.x;
  float4 v = make_float4(0.f, 0.f, 0.f, 0.f);
  if (t < T_STEPS) {
    const int tok = (t == 0) ? 0 : inputs[t];
    v = *(const float4*)&emb[(size_t)tok * KDIM + tid * 4];
  }
  *(float4*)&X[(size_t)t * KDIM + tid * 4] = v;
}

// ---------------- NT GEMM: A f32 x B f32 -> C f64, fp64 accumulate ----------
__global__ __launch_bounds__(256) void k_gemm_ffd(const float* __restrict__ A,
                                                  const float* __restrict__ B,
                                                  const float* __restrict__ bias,
                                                  double* __restrict__ C,
                                                  int N, int K) {
  __shared__ float As[32][68];
  __shared__ float Bs[32][68];
  const int tid = threadIdx.x;
  const int bx = blockIdx.x, by = blockIdx.y;
  const int lr = tid >> 2;            // 0..63
  const int lk = (tid & 3) * 8;       // 0,8,16,24
  const float* Ap = A + (size_t)(by * 64 + lr) * K + lk;
  const float* Bp = B + (size_t)(bx * 64 + lr) * K + lk;
  const int r0 = (tid >> 4) * 4;
  const int c0 = (tid & 15) * 4;
  double acc[4][4] = {};
  for (int kc = 0; kc < K; kc += 32) {
    const float4 a0 = *(const float4*)(Ap + kc);
    const float4 a1 = *(const float4*)(Ap + kc + 4);
    const float4 b0 = *(const float4*)(Bp + kc);
    const float4 b1 = *(const float4*)(Bp + kc + 4);
    __syncthreads();
    As[lk+0][lr]=a0.x; As[lk+1][lr]=a0.y; As[lk+2][lr]=a0.z; As[lk+3][lr]=a0.w;
    As[lk+4][lr]=a1.x; As[lk+5][lr]=a1.y; As[lk+6][lr]=a1.z; As[lk+7][lr]=a1.w;
    Bs[lk+0][lr]=b0.x; Bs[lk+1][lr]=b0.y; Bs[lk+2][lr]=b0.z; Bs[lk+3][lr]=b0.w;
    Bs[lk+4][lr]=b1.x; Bs[lk+5][lr]=b1.y; Bs[lk+6][lr]=b1.z; Bs[lk+7][lr]=b1.w;
    __syncthreads();
#pragma unroll
    for (int kk = 0; kk < 32; ++kk) {
      const float4 av = *(const float4*)&As[kk][r0];
      const float4 bv = *(const float4*)&Bs[kk][c0];
      const double aa[4] = {av.x, av.y, av.z, av.w};
      const double bb[4] = {bv.x, bv.y, bv.z, bv.w};
#pragma unroll
      for (int i = 0; i < 4; ++i)
#pragma unroll
        for (int j = 0; j < 4; ++j)
          acc[i][j] = fma(aa[i], bb[j], acc[i][j]);
    }
  }
  const int row = by * 64 + r0;
  const int col = bx * 64 + c0;
#pragma unroll
  for (int i = 0; i < 4; ++i)
#pragma unroll
    for (int j = 0; j < 4; ++j)
      C[(size_t)(row + i) * N + col + j] = acc[i][j] + (double)bias[col + j];
}

// ---------------- NT GEMM: A f64 x B f32 -> C f64, fp64 accumulate ----------
__global__ __launch_bounds__(256) void k_gemm_dfd(const double* __restrict__ A,
                                                  const float* __restrict__ B,
                                                  const float* __restrict__ bias,
                                                  double* __restrict__ C,
                                                  int N, int K) {
  __shared__ double As[32][68];
  __shared__ float  Bs[32][68];
  const int tid = threadIdx.x;
  const int bx = blockIdx.x, by = blockIdx.y;
  const int lr = tid >> 2;
  const int lk = (tid & 3) * 8;
  const double* Ap = A + (size_t)(by * 64 + lr) * K + lk;
  const float*  Bp = B + (size_t)(bx * 64 + lr) * K + lk;
  const int r0 = (tid >> 4) * 4;
  const int c0 = (tid & 15) * 4;
  double acc[4][4] = {};
  for (int kc = 0; kc < K; kc += 32) {
    double ar[8];
#pragma unroll
    for (int q = 0; q < 8; ++q) ar[q] = Ap[kc + q];
    const float4 b0 = *(const float4*)(Bp + kc);
    const float4 b1 = *(const float4*)(Bp + kc + 4);
    __syncthreads();
#pragma unroll
    for (int q = 0; q < 8; ++q) As[lk + q][lr] = ar[q];
    Bs[lk+0][lr]=b0.x; Bs[lk+1][lr]=b0.y; Bs[lk+2][lr]=b0.z; Bs[lk+3][lr]=b0.w;
    Bs[lk+4][lr]=b1.x; Bs[lk+5][lr]=b1.y; Bs[lk+6][lr]=b1.z; Bs[lk+7][lr]=b1.w;
    __syncthreads();
#pragma unroll
    for (int kk = 0; kk < 32; ++kk) {
      const double aa[4] = {As[kk][r0+0], As[kk][r0+1], As[kk][r0+2], As[kk][r0+3]};
      const float4 bv = *(const float4*)&Bs[kk][c0];
      const double bb[4] = {bv.x, bv.y, bv.z, bv.w};
#pragma unroll
      for (int i = 0; i < 4; ++i)
#pragma unroll
        for (int j = 0; j < 4; ++j)
          acc[i][j] = fma(aa[i], bb[j], acc[i][j]);
    }
  }
  const int row = by * 64 + r0;
  const int col = bx * 64 + c0;
#pragma unroll
  for (int i = 0; i < 4; ++i)
#pragma unroll
    for (int j = 0; j < 4; ++j)
      C[(size_t)(row + i) * N + col + j] = acc[i][j] + (double)bias[col + j];
}

// -------------------- persistent GRU recurrence (single launch) -------------
// 64 blocks x 512 threads. Wave w of block b owns h-indices {b*16+w*2, +1};
// W_hh rows in registers (fp32, 96 VGPR); fp64 dots + gates (bit-identical
// to the passing round-5 k_step).
// Grid barrier: RMW-free sense-indexed flag array. Block b release-stores
// flags[t&1][b]=t+1 (own 64B line, parallel at the LLC); lanes 0..63 of
// wave 0 each poll one block's flag, exit via __all(v >= t+1).
__global__ __launch_bounds__(512, 2) void k_recur(const float* __restrict__ z,
                                                  const float* __restrict__ Whh,
                                                  const float* __restrict__ bhh,
                                                  const double* __restrict__ GI,
                                                  double* H, int* flags) {
  __shared__ double hs[1024];
  const int tid = threadIdx.x;
  const int w = tid >> 6, l = tid & 63;
  const int ibase = blockIdx.x * 16 + w * 2;
  float wreg[6][16];
#pragma unroll
  for (int il = 0; il < 2; ++il)
#pragma unroll
    for (int g = 0; g < 3; ++g) {
      const float* wp = Whh + (size_t)(g * 1024 + ibase + il) * 1024 + l;
#pragma unroll
      for (int m = 0; m < 16; ++m) wreg[il * 3 + g][m] = wp[m * 64];
    }
  double bh[6];
#pragma unroll
  for (int il = 0; il < 2; ++il)
#pragma unroll
    for (int g = 0; g < 3; ++g) bh[il * 3 + g] = (double)bhh[g * 1024 + ibase + il];

  for (int t = 0; t < T_STEPS; ++t) {
    if (t == 0) {
      hs[tid]       = (double)z[tid];
      hs[tid + 512] = (double)z[tid + 512];
    } else {
      const double* hp = H + (size_t)(t - 1) * 1024;
      hs[tid]       = __hip_atomic_load(hp + tid,
                        __ATOMIC_RELAXED, __HIP_MEMORY_SCOPE_AGENT);
      hs[tid + 512] = __hip_atomic_load(hp + tid + 512,
                        __ATOMIC_RELAXED, __HIP_MEMORY_SCOPE_AGENT);
    }
    __syncthreads();
    double gi[6];
    {
      const double* gp = GI + (size_t)t * 3072;
#pragma unroll
      for (int il = 0; il < 2; ++il)
#pragma unroll
        for (int g = 0; g < 3; ++g) gi[il * 3 + g] = gp[g * 1024 + ibase + il];
    }
    double s[6] = {0.0, 0.0, 0.0, 0.0, 0.0, 0.0};
#pragma unroll
    for (int m = 0; m < 16; ++m) {
      const double hv = hs[l + 64 * m];
#pragma unroll
      for (int rr = 0; rr < 6; ++rr) s[rr] = fma((double)wreg[rr][m], hv, s[rr]);
    }
#pragma unroll
    for (int rr = 0; rr < 6; ++rr) {
      double v = s[rr];
#pragma unroll
      for (int mk = 32; mk >= 1; mk >>= 1) v += __shfl_xor(v, mk, 64);
      s[rr] = v;
    }
    if (l < 2) {                 // lane 0 -> il=0, lane 1 -> il=1
      const int il = l;
      const double r  = 1.0 / (1.0 + exp(-(gi[il * 3 + 0] + s[il * 3 + 0] + bh[il * 3 + 0])));
      const double zg = 1.0 / (1.0 + exp(-(gi[il * 3 + 1] + s[il * 3 + 1] + bh[il * 3 + 1])));
      const double n  = tanh(gi[il * 3 + 2] + r * (s[il * 3 + 2] + bh[il * 3 + 2]));
      const int gidx = ibase + il;
      const double hn = (1.0 - zg) * n + zg * hs[gidx];
      __hip_atomic_store(H + (size_t)t * 1024 + gidx, hn,
                         __ATOMIC_RELAXED, __HIP_MEMORY_SCOPE_AGENT);
    }
    __syncthreads();   // all waves' H stores drained (vmcnt 0 before barrier)
    {
      const int target = t + 1;
      const int p = t & 1;
      if (tid == 0)
        __hip_atomic_store(flags + (size_t)(p * 64 + blockIdx.x) * 16, target,
                           __ATOMIC_RELEASE, __HIP_MEMORY_SCOPE_AGENT);
      if (tid < 64) {
        int* fp = flags + (size_t)(p * 64 + tid) * 16;
        while (true) {
          const int v = __hip_atomic_load(fp, __ATOMIC_ACQUIRE,
                                          __HIP_MEMORY_SCOPE_AGENT);
          if (__all(v >= target)) break;
          __builtin_amdgcn_s_sleep(1);
        }
      }
      __syncthreads();
    }
  }
}

// ------- logits GEMM (f64) + per-chunk fp32 top-2 candidates + loss stats ---
__global__ __launch_bounds__(256) void k_logits(const double* __restrict__ E,
                                                const float* __restrict__ emb,
                                                const float* __restrict__ out_b,
                                                const int* __restrict__ inputs,
                                                float* __restrict__ candL,
                                                int* __restrict__ candI,
                                                float* __restrict__ Psum,
                                                float* __restrict__ Ttgt) {
  __shared__ double As[32][68];
  __shared__ float  Bs[32][68];
  const int tid = threadIdx.x;
  const int bx = blockIdx.x, by = blockIdx.y;
  const int lr = tid >> 2;
  const int lk = (tid & 3) * 8;
  const int brow = bx * 64 + lr;
  const double* Ap = E + (size_t)(by * 64 + lr) * KDIM + lk;
  const float*  Bp = emb + (size_t)brow * KDIM + lk;
  const bool bvalid = (brow < NV);
  const int r0 = (tid >> 4) * 4;
  const int c0 = (tid & 15) * 4;
  double acc[4][4] = {};
  for (int kc = 0; kc < KDIM; kc += 32) {
    double ar[8];
#pragma unroll
    for (int q = 0; q < 8; ++q) ar[q] = Ap[kc + q];
    float4 b0 = make_float4(0.f, 0.f, 0.f, 0.f);
    float4 b1 = make_float4(0.f, 0.f, 0.f, 0.f);
    if (bvalid) { b0 = *(const float4*)(Bp + kc); b1 = *(const float4*)(Bp + kc + 4); }
    __syncthreads();
#pragma unroll
    for (int q = 0; q < 8; ++q) As[lk + q][lr] = ar[q];
    Bs[lk+0][lr]=b0.x; Bs[lk+1][lr]=b0.y; Bs[lk+2][lr]=b0.z; Bs[lk+3][lr]=b0.w;
    Bs[lk+4][lr]=b1.x; Bs[lk+5][lr]=b1.y; Bs[lk+6][lr]=b1.z; Bs[lk+7][lr]=b1.w;
    __syncthreads();
#pragma unroll
    for (int kk = 0; kk < 32; ++kk) {
      const double aa[4] = {As[kk][r0+0], As[kk][r0+1], As[kk][r0+2], As[kk][r0+3]};
      const float4 bv = *(const float4*)&Bs[kk][c0];
      const double bb[4] = {bv.x, bv.y, bv.z, bv.w};
#pragma unroll
      for (int i = 0; i < 4; ++i)
#pragma unroll
        for (int j = 0; j < 4; ++j)
          acc[i][j] = fma(aa[i], bb[j], acc[i][j]);
    }
  }
  const int colb = bx * 64 + c0;
#pragma unroll
  for (int i = 0; i < 4; ++i) {
    const int s = by * 64 + r0 + i;
    const bool valid = (s < T_STEPS);
    const int tgt = valid ? inputs[s + 1] : -1;
    float L1 = -3e38f, L2 = -3e38f;
    int   i1 = 0x7FFFFFFF, i2 = 0x7FFFFFFF;
    float se = 0.f, tv = -INFINITY;
#pragma unroll
    for (int j = 0; j < 4; ++j) {
      const int v = colb + j;
      if (v < NV) {
        const double lgd = acc[i][j] + (double)out_b[v];
        const float L = (float)lgd;           // np's fp32 logit (bit-matched)
        se += expf((float)(lgd - 0.01));
        if (v == tgt) tv = (float)lgd;
        if (L > L1 || (L == L1 && v < i1)) { L2 = L1; i2 = i1; L1 = L; i1 = v; }
        else if (L > L2 || (L == L2 && v < i2)) { L2 = L; i2 = v; }
      }
    }
#pragma unroll
    for (int mk = 1; mk <= 8; mk <<= 1) {
      const float oL1 = __shfl_xor(L1, mk, 64); const int oi1 = __shfl_xor(i1, mk, 64);
      const float oL2 = __shfl_xor(L2, mk, 64); const int oi2 = __shfl_xor(i2, mk, 64);
      if (oL1 > L1 || (oL1 == L1 && oi1 < i1)) { L2 = L1; i2 = i1; L1 = oL1; i1 = oi1; }
      else if (oL1 > L2 || (oL1 == L2 && oi1 < i2)) { L2 = oL1; i2 = oi1; }
      if (oL2 > L1 || (oL2 == L1 && oi2 < i1)) { L2 = L1; i2 = i1; L1 = oL2; i1 = oi2; }
      else if (oL2 > L2 || (oL2 == L2 && oi2 < i2)) { L2 = oL2; i2 = oi2; }
      se += __shfl_xor(se, mk, 64);
      tv = fmaxf(tv, __shfl_xor(tv, mk, 64));
    }
    if (((tid & 15) == 0) && valid) {
      const size_t p = (size_t)s * (2 * NCH) + 2 * bx;
      candL[p] = L1;     candI[p] = i1;
      candL[p + 1] = L2; candI[p + 1] = i2;
      atomicAdd(&Psum[s], se);
      if (tv > -1e30f) Ttgt[s] = tv;
    }
  }
}

// --------- preds: np-faithful fp32 log_softmax quantized argmax -------------
__global__ __launch_bounds__(256) void k_preds(const float* __restrict__ candL,
                                               const int* __restrict__ candI,
                                               float* __restrict__ out) {
  __shared__ float sL[256];
  __shared__ int   sI[256];
  const int s = blockIdx.x;        // 0..1022
  const int tid = threadIdx.x;
  const int n = 2 * NCH;           // 1564
  const size_t base = (size_t)s * n;
  float m = -3e38f;
  for (int c = tid; c < n; c += 256) m = fmaxf(m, candL[base + c]);
  sL[tid] = m; __syncthreads();
  for (int st = 128; st > 0; st >>= 1) {
    if (tid < st) sL[tid] = fmaxf(sL[tid], sL[tid + st]);
    __syncthreads();
  }
  const float Lmax = sL[0];
  __syncthreads();
  float bq = -3e38f; int bi = 0x7FFFFFFF;
  for (int c = tid; c < n; c += 256) {
    const float L = candL[base + c];
    const int   v = candI[base + c];
    const float d = L - Lmax;              // Sterbenz-exact
    const float q = d - 10.8125f;          // fp32 bucket quantization
    if (q > bq || (q == bq && v < bi)) { bq = q; bi = v; }
  }
  sL[tid] = bq; sI[tid] = bi; __syncthreads();
  for (int st = 128; st > 0; st >>= 1) {
    if (tid < st) {
      if (sL[tid + st] > sL[tid] ||
          (sL[tid + st] == sL[tid] && sI[tid + st] < sI[tid])) {
        sL[tid] = sL[tid + st]; sI[tid] = sI[tid + st];
      }
    }
    __syncthreads();
  }
  if (tid == 0) out[2 + s] = (float)sI[0];
}

// ------------------------------------------------ final loss ----------------
__global__ __launch_bounds__(1024) void k_finish(const float* __restrict__ Psum,
                                                 const float* __restrict__ Ttgt,
                                                 float* __restrict__ out) {
  __shared__ double red[1024];
  const int s = threadIdx.x;
  double ls = 0.0;
  if (s < T_STEPS) ls = 0.01 + log((double)Psum[s]) - (double)Ttgt[s];
  red[s] = ls;
  __syncthreads();
  for (int st = 512; st > 0; st >>= 1) {
    if (s < st) red[s] += red[s + st];
    __syncthreads();
  }
  if (s == 0) out[0] = (float)red[0];
  if (s == 1) out[1] = 0.f;
}

// ----------------------------------------------------------------- launch ---
extern "C" void kernel_launch(void* const* d_in, const int* in_sizes, int n_in,
                              void* d_out, int out_size, void* d_ws, size_t ws_size,
                              hipStream_t stream) {
  const int*   inputs = (const int*)  d_in[0];
  const float* z      = (const float*)d_in[1];
  const float* emb    = (const float*)d_in[2];
  const float* out_b  = (const float*)d_in[3];
  const float* h2eW   = (const float*)d_in[4];
  const float* h2eb   = (const float*)d_in[5];
  const float* Wih    = (const float*)d_in[6];
  const float* Whh    = (const float*)d_in[7];
  const float* bih    = (const float*)d_in[8];
  const float* bhh    = (const float*)d_in[9];

  char* ws8 = (char*)d_ws;
  int*    flags = (int*)ws8;                             // [0, 8192)
  float*  Psum = (float*)(ws8 + 8192);                   // 4 KiB
  float*  Ttgt = (float*)(ws8 + 12288);                  // 4 KiB
  float*  X    = (float*)(ws8 + 24576);                  // 4 MiB
  char*   GIb  = ws8 + 24576 + (4u << 20);               // 24 MiB region
  double* GI   = (double*)GIb;
  double* E    = GI;                                     // 8 MiB overlay
  float*  candL = (float*)(GIb + (8u << 20));            // 6.11 MiB
  int*    candI = (int*)  (GIb + (8u << 20) + 6815744);  // 6.11 MiB
  double* H    = (double*)(ws8 + 24576 + (28u << 20));   // 8 MiB
  float*  out  = (float*)d_out;

  hipMemsetAsync(ws8, 0, 16384, stream);                 // flags + Psum + Ttgt

  k_gather<<<1024, 256, 0, stream>>>(inputs, emb, X);
  k_gemm_ffd<<<dim3(48, 16), 256, 0, stream>>>(X, Wih, bih, GI, 3072, KDIM);
  k_recur<<<64, 512, 0, stream>>>(z, Whh, bhh, GI, H, flags);
  k_gemm_dfd<<<dim3(16, 16), 256, 0, stream>>>(H, h2eW, h2eb, E, KDIM, KDIM);
  k_logits<<<dim3(NCH, 16), 256, 0, stream>>>(E, emb, out_b, inputs,
                                              candL, candI, Psum, Ttgt);
  k_preds<<<T_STEPS, 256, 0, stream>>>(candL, candI, out);
  k_finish<<<1, 1024, 0, stream>>>(Psum, Ttgt, out);
}

// Round 8
// 11998.830 us; speedup vs baseline: 1.2326x; 1.0264x over previous
//
#include <hip/hip_runtime.h>
#include <math.h>

#define NV      50000
#define T_STEPS 1023
#define KDIM    1024
#define NCH     782   // ceil(50000/64)
typedef unsigned long long ull;

// ws layout (bytes):
//   [0, 512)             flags int[2][64] (packed grid barrier, sense by t&1)
//   [8192, 12288)        Psum  f32[1024]
//   [12288, 16384)       Ttgt  f32[1024]
//   [24K, 24K+4M)        X     f32[1024*1024]
//   [24K+4M, 24K+28M)    GI    f64[1024*3072]; after recurrence:
//                          [+0, +8M)       E f64[1024*1024]
//                          [+8M, +14.5M)   candL f32[1024*1564]
//                          [+14.5M,+21M)   candI i32[1024*1564]
//   [24K+28M, 24K+36M)   H     f64[1024*1024]
// total ~36.02 MiB

// ---------------------------------------------------------------- gather ----
__global__ __launch_bounds__(256) void k_gather(const int* __restrict__ inputs,
                                                const float* __restrict__ emb,
                                                float* __restrict__ X) {
  const int t = blockIdx.x;      // 0..1023 (row 1023 = zero pad)
  const int tid = threadIdx.x;
  float4 v = make_float4(0.f, 0.f, 0.f, 0.f);
  if (t < T_STEPS) {
    const int tok = (t == 0) ? 0 : inputs[t];
    v = *(const float4*)&emb[(size_t)tok * KDIM + tid * 4];
  }
  *(float4*)&X[(size_t)t * KDIM + tid * 4] = v;
}

// ---------------- NT GEMM: A f32 x B f32 -> C f64, fp64 accumulate ----------
__global__ __launch_bounds__(256) void k_gemm_ffd(const float* __restrict__ A,
                                                  const float* __restrict__ B,
                                                  const float* __restrict__ bias,
                                                  double* __restrict__ C,
                                                  int N, int K) {
  __shared__ float As[32][68];
  __shared__ float Bs[32][68];
  const int tid = threadIdx.x;
  const int bx = blockIdx.x, by = blockIdx.y;
  const int lr = tid >> 2;            // 0..63
  const int lk = (tid & 3) * 8;       // 0,8,16,24
  const float* Ap = A + (size_t)(by * 64 + lr) * K + lk;
  const float* Bp = B + (size_t)(bx * 64 + lr) * K + lk;
  const int r0 = (tid >> 4) * 4;
  const int c0 = (tid & 15) * 4;
  double acc[4][4] = {};
  for (int kc = 0; kc < K; kc += 32) {
    const float4 a0 = *(const float4*)(Ap + kc);
    const float4 a1 = *(const float4*)(Ap + kc + 4);
    const float4 b0 = *(const float4*)(Bp + kc);
    const float4 b1 = *(const float4*)(Bp + kc + 4);
    __syncthreads();
    As[lk+0][lr]=a0.x; As[lk+1][lr]=a0.y; As[lk+2][lr]=a0.z; As[lk+3][lr]=a0.w;
    As[lk+4][lr]=a1.x; As[lk+5][lr]=a1.y; As[lk+6][lr]=a1.z; As[lk+7][lr]=a1.w;
    Bs[lk+0][lr]=b0.x; Bs[lk+1][lr]=b0.y; Bs[lk+2][lr]=b0.z; Bs[lk+3][lr]=b0.w;
    Bs[lk+4][lr]=b1.x; Bs[lk+5][lr]=b1.y; Bs[lk+6][lr]=b1.z; Bs[lk+7][lr]=b1.w;
    __syncthreads();
#pragma unroll
    for (int kk = 0; kk < 32; ++kk) {
      const float4 av = *(const float4*)&As[kk][r0];
      const float4 bv = *(const float4*)&Bs[kk][c0];
      const double aa[4] = {av.x, av.y, av.z, av.w};
      const double bb[4] = {bv.x, bv.y, bv.z, bv.w};
#pragma unroll
      for (int i = 0; i < 4; ++i)
#pragma unroll
        for (int j = 0; j < 4; ++j)
          acc[i][j] = fma(aa[i], bb[j], acc[i][j]);
    }
  }
  const int row = by * 64 + r0;
  const int col = bx * 64 + c0;
#pragma unroll
  for (int i = 0; i < 4; ++i)
#pragma unroll
    for (int j = 0; j < 4; ++j)
      C[(size_t)(row + i) * N + col + j] = acc[i][j] + (double)bias[col + j];
}

// ---------------- NT GEMM: A f64 x B f32 -> C f64, fp64 accumulate ----------
__global__ __launch_bounds__(256) void k_gemm_dfd(const double* __restrict__ A,
                                                  const float* __restrict__ B,
                                                  const float* __restrict__ bias,
                                                  double* __restrict__ C,
                                                  int N, int K) {
  __shared__ double As[32][68];
  __shared__ float  Bs[32][68];
  const int tid = threadIdx.x;
  const int bx = blockIdx.x, by = blockIdx.y;
  const int lr = tid >> 2;
  const int lk = (tid & 3) * 8;
  const double* Ap = A + (size_t)(by * 64 + lr) * K + lk;
  const float*  Bp = B + (size_t)(bx * 64 + lr) * K + lk;
  const int r0 = (tid >> 4) * 4;
  const int c0 = (tid & 15) * 4;
  double acc[4][4] = {};
  for (int kc = 0; kc < K; kc += 32) {
    double ar[8];
#pragma unroll
    for (int q = 0; q < 8; ++q) ar[q] = Ap[kc + q];
    const float4 b0 = *(const float4*)(Bp + kc);
    const float4 b1 = *(const float4*)(Bp + kc + 4);
    __syncthreads();
#pragma unroll
    for (int q = 0; q < 8; ++q) As[lk + q][lr] = ar[q];
    Bs[lk+0][lr]=b0.x; Bs[lk+1][lr]=b0.y; Bs[lk+2][lr]=b0.z; Bs[lk+3][lr]=b0.w;
    Bs[lk+4][lr]=b1.x; Bs[lk+5][lr]=b1.y; Bs[lk+6][lr]=b1.z; Bs[lk+7][lr]=b1.w;
    __syncthreads();
#pragma unroll
    for (int kk = 0; kk < 32; ++kk) {
      const double aa[4] = {As[kk][r0+0], As[kk][r0+1], As[kk][r0+2], As[kk][r0+3]};
      const float4 bv = *(const float4*)&Bs[kk][c0];
      const double bb[4] = {bv.x, bv.y, bv.z, bv.w};
#pragma unroll
      for (int i = 0; i < 4; ++i)
#pragma unroll
        for (int j = 0; j < 4; ++j)
          acc[i][j] = fma(aa[i], bb[j], acc[i][j]);
    }
  }
  const int row = by * 64 + r0;
  const int col = bx * 64 + c0;
#pragma unroll
  for (int i = 0; i < 4; ++i)
#pragma unroll
    for (int j = 0; j < 4; ++j)
      C[(size_t)(row + i) * N + col + j] = acc[i][j] + (double)bias[col + j];
}

// -------------------- persistent GRU recurrence (single launch) -------------
// 64 blocks x 512 threads. Wave w of block b owns h-indices {b*16+w*2, +1};
// W_hh rows in registers (fp32); fp64 dots + gates (bit-identical to the
// passing round-5 k_step).
// Grid barrier per step: packed flag array flags[t&1][64] (one coalesced
// 256B poll), RELAXED spin + single ACQUIRE fence on exit, RELEASE publish.
// GI row for t+1 prefetched before the spin (latency hides under barrier).
__global__ __launch_bounds__(512, 2) void k_recur(const float* __restrict__ z,
                                                  const float* __restrict__ Whh,
                                                  const float* __restrict__ bhh,
                                                  const double* __restrict__ GI,
                                                  double* H, int* flags) {
  __shared__ double hs[1024];
  const int tid = threadIdx.x;
  const int w = tid >> 6, l = tid & 63;
  const int ibase = blockIdx.x * 16 + w * 2;
  float wreg[6][16];
#pragma unroll
  for (int il = 0; il < 2; ++il)
#pragma unroll
    for (int g = 0; g < 3; ++g) {
      const float* wp = Whh + (size_t)(g * 1024 + ibase + il) * 1024 + l;
#pragma unroll
      for (int m = 0; m < 16; ++m) wreg[il * 3 + g][m] = wp[m * 64];
    }
  double bh[6];
#pragma unroll
  for (int il = 0; il < 2; ++il)
#pragma unroll
    for (int g = 0; g < 3; ++g) bh[il * 3 + g] = (double)bhh[g * 1024 + ibase + il];

  // h_{-1} = z; GI row 0 preloaded
  hs[tid]       = (double)z[tid];
  hs[tid + 512] = (double)z[tid + 512];
  double gi[6];
#pragma unroll
  for (int il = 0; il < 2; ++il)
#pragma unroll
    for (int g = 0; g < 3; ++g) gi[il * 3 + g] = GI[g * 1024 + ibase + il];
  __syncthreads();

  for (int t = 0; t < T_STEPS; ++t) {
    double s[6] = {0.0, 0.0, 0.0, 0.0, 0.0, 0.0};
#pragma unroll
    for (int m = 0; m < 16; ++m) {
      const double hv = hs[l + 64 * m];
#pragma unroll
      for (int rr = 0; rr < 6; ++rr) s[rr] = fma((double)wreg[rr][m], hv, s[rr]);
    }
#pragma unroll
    for (int rr = 0; rr < 6; ++rr) {
      double v = s[rr];
#pragma unroll
      for (int mk = 32; mk >= 1; mk >>= 1) v += __shfl_xor(v, mk, 64);
      s[rr] = v;
    }
    if (l < 2) {                 // lane 0 -> il=0, lane 1 -> il=1
      const int il = l;
      const double r  = 1.0 / (1.0 + exp(-(gi[il * 3 + 0] + s[il * 3 + 0] + bh[il * 3 + 0])));
      const double zg = 1.0 / (1.0 + exp(-(gi[il * 3 + 1] + s[il * 3 + 1] + bh[il * 3 + 1])));
      const double n  = tanh(gi[il * 3 + 2] + r * (s[il * 3 + 2] + bh[il * 3 + 2]));
      const int gidx = ibase + il;
      const double hn = (1.0 - zg) * n + zg * hs[gidx];
      __hip_atomic_store(H + (size_t)t * 1024 + gidx, hn,
                         __ATOMIC_RELAXED, __HIP_MEMORY_SCOPE_AGENT);
    }
    const bool more = (t + 1 < T_STEPS);
    // prefetch GI row t+1 (independent of h; completes during the spin)
    double gin[6] = {0.0, 0.0, 0.0, 0.0, 0.0, 0.0};
    if (more) {
      const double* gp = GI + (size_t)(t + 1) * 3072;
#pragma unroll
      for (int il = 0; il < 2; ++il)
#pragma unroll
        for (int g = 0; g < 3; ++g) gin[il * 3 + g] = gp[g * 1024 + ibase + il];
    }
    __syncthreads();   // all waves' H stores drained (vmcnt 0 before barrier)
    if (more) {
      const int target = t + 1;
      const int p = t & 1;
      if (tid == 0)
        __hip_atomic_store(flags + p * 64 + blockIdx.x, target,
                           __ATOMIC_RELEASE, __HIP_MEMORY_SCOPE_AGENT);
      if (tid < 64) {
        const int* fp = flags + p * 64 + tid;
        while (true) {
          const int v = __hip_atomic_load(fp, __ATOMIC_RELAXED,
                                          __HIP_MEMORY_SCOPE_AGENT);
          if (__all(v >= target)) break;
          __builtin_amdgcn_s_sleep(1);
        }
        __builtin_amdgcn_fence(__ATOMIC_ACQUIRE, "agent");
      }
      __syncthreads();
      const double* hp = H + (size_t)t * 1024;
      hs[tid]       = __hip_atomic_load(hp + tid,
                        __ATOMIC_RELAXED, __HIP_MEMORY_SCOPE_AGENT);
      hs[tid + 512] = __hip_atomic_load(hp + tid + 512,
                        __ATOMIC_RELAXED, __HIP_MEMORY_SCOPE_AGENT);
#pragma unroll
      for (int q = 0; q < 6; ++q) gi[q] = gin[q];
      __syncthreads();
    }
  }
}

// ------- logits GEMM (f64) + per-chunk fp32 top-2 candidates + loss stats ---
__global__ __launch_bounds__(256) void k_logits(const double* __restrict__ E,
                                                const float* __restrict__ emb,
                                                const float* __restrict__ out_b,
                                                const int* __restrict__ inputs,
                                                float* __restrict__ candL,
                                                int* __restrict__ candI,
                                                float* __restrict__ Psum,
                                                float* __restrict__ Ttgt) {
  __shared__ double As[32][68];
  __shared__ float  Bs[32][68];
  const int tid = threadIdx.x;
  const int bx = blockIdx.x, by = blockIdx.y;
  const int lr = tid >> 2;
  const int lk = (tid & 3) * 8;
  const int brow = bx * 64 + lr;
  const double* Ap = E + (size_t)(by * 64 + lr) * KDIM + lk;
  const float*  Bp = emb + (size_t)brow * KDIM + lk;
  const bool bvalid = (brow < NV);
  const int r0 = (tid >> 4) * 4;
  const int c0 = (tid & 15) * 4;
  double acc[4][4] = {};
  for (int kc = 0; kc < KDIM; kc += 32) {
    double ar[8];
#pragma unroll
    for (int q = 0; q < 8; ++q) ar[q] = Ap[kc + q];
    float4 b0 = make_float4(0.f, 0.f, 0.f, 0.f);
    float4 b1 = make_float4(0.f, 0.f, 0.f, 0.f);
    if (bvalid) { b0 = *(const float4*)(Bp + kc); b1 = *(const float4*)(Bp + kc + 4); }
    __syncthreads();
#pragma unroll
    for (int q = 0; q < 8; ++q) As[lk + q][lr] = ar[q];
    Bs[lk+0][lr]=b0.x; Bs[lk+1][lr]=b0.y; Bs[lk+2][lr]=b0.z; Bs[lk+3][lr]=b0.w;
    Bs[lk+4][lr]=b1.x; Bs[lk+5][lr]=b1.y; Bs[lk+6][lr]=b1.z; Bs[lk+7][lr]=b1.w;
    __syncthreads();
#pragma unroll
    for (int kk = 0; kk < 32; ++kk) {
      const double aa[4] = {As[kk][r0+0], As[kk][r0+1], As[kk][r0+2], As[kk][r0+3]};
      const float4 bv = *(const float4*)&Bs[kk][c0];
      const double bb[4] = {bv.x, bv.y, bv.z, bv.w};
#pragma unroll
      for (int i = 0; i < 4; ++i)
#pragma unroll
        for (int j = 0; j < 4; ++j)
          acc[i][j] = fma(aa[i], bb[j], acc[i][j]);
    }
  }
  const int colb = bx * 64 + c0;
#pragma unroll
  for (int i = 0; i < 4; ++i) {
    const int s = by * 64 + r0 + i;
    const bool valid = (s < T_STEPS);
    const int tgt = valid ? inputs[s + 1] : -1;
    float L1 = -3e38f, L2 = -3e38f;
    int   i1 = 0x7FFFFFFF, i2 = 0x7FFFFFFF;
    float se = 0.f, tv = -INFINITY;
#pragma unroll
    for (int j = 0; j < 4; ++j) {
      const int v = colb + j;
      if (v < NV) {
        const double lgd = acc[i][j] + (double)out_b[v];
        const float L = (float)lgd;           // np's fp32 logit (bit-matched)
        se += expf((float)(lgd - 0.01));
        if (v == tgt) tv = (float)lgd;
        if (L > L1 || (L == L1 && v < i1)) { L2 = L1; i2 = i1; L1 = L; i1 = v; }
        else if (L > L2 || (L == L2 && v < i2)) { L2 = L; i2 = v; }
      }
    }
#pragma unroll
    for (int mk = 1; mk <= 8; mk <<= 1) {
      const float oL1 = __shfl_xor(L1, mk, 64); const int oi1 = __shfl_xor(i1, mk, 64);
      const float oL2 = __shfl_xor(L2, mk, 64); const int oi2 = __shfl_xor(i2, mk, 64);
      if (oL1 > L1 || (oL1 == L1 && oi1 < i1)) { L2 = L1; i2 = i1; L1 = oL1; i1 = oi1; }
      else if (oL1 > L2 || (oL1 == L2 && oi1 < i2)) { L2 = oL1; i2 = oi1; }
      if (oL2 > L1 || (oL2 == L1 && oi2 < i1)) { L2 = L1; i2 = i1; L1 = oL2; i1 = oi2; }
      else if (oL2 > L2 || (oL2 == L2 && oi2 < i2)) { L2 = oL2; i2 = oi2; }
      se += __shfl_xor(se, mk, 64);
      tv = fmaxf(tv, __shfl_xor(tv, mk, 64));
    }
    if (((tid & 15) == 0) && valid) {
      const size_t p = (size_t)s * (2 * NCH) + 2 * bx;
      candL[p] = L1;     candI[p] = i1;
      candL[p + 1] = L2; candI[p + 1] = i2;
      atomicAdd(&Psum[s], se);
      if (tv > -1e30f) Ttgt[s] = tv;
    }
  }
}

// --------- preds: np-faithful fp32 log_softmax quantized argmax -------------
__global__ __launch_bounds__(256) void k_preds(const float* __restrict__ candL,
                                               const int* __restrict__ candI,
                                               float* __restrict__ out) {
  __shared__ float sL[256];
  __shared__ int   sI[256];
  const int s = blockIdx.x;        // 0..1022
  const int tid = threadIdx.x;
  const int n = 2 * NCH;           // 1564
  const size_t base = (size_t)s * n;
  float m = -3e38f;
  for (int c = tid; c < n; c += 256) m = fmaxf(m, candL[base + c]);
  sL[tid] = m; __syncthreads();
  for (int st = 128; st > 0; st >>= 1) {
    if (tid < st) sL[tid] = fmaxf(sL[tid], sL[tid + st]);
    __syncthreads();
  }
  const float Lmax = sL[0];
  __syncthreads();
  float bq = -3e38f; int bi = 0x7FFFFFFF;
  for (int c = tid; c < n; c += 256) {
    const float L = candL[base + c];
    const int   v = candI[base + c];
    const float d = L - Lmax;              // Sterbenz-exact
    const float q = d - 10.8125f;          // fp32 bucket quantization
    if (q > bq || (q == bq && v < bi)) { bq = q; bi = v; }
  }
  sL[tid] = bq; sI[tid] = bi; __syncthreads();
  for (int st = 128; st > 0; st >>= 1) {
    if (tid < st) {
      if (sL[tid + st] > sL[tid] ||
          (sL[tid + st] == sL[tid] && sI[tid + st] < sI[tid])) {
        sL[tid] = sL[tid + st]; sI[tid] = sI[tid + st];
      }
    }
    __syncthreads();
  }
  if (tid == 0) out[2 + s] = (float)sI[0];
}

// ------------------------------------------------ final loss ----------------
__global__ __launch_bounds__(1024) void k_finish(const float* __restrict__ Psum,
                                                 const float* __restrict__ Ttgt,
                                                 float* __restrict__ out) {
  __shared__ double red[1024];
  const int s = threadIdx.x;
  double ls = 0.0;
  if (s < T_STEPS) ls = 0.01 + log((double)Psum[s]) - (double)Ttgt[s];
  red[s] = ls;
  __syncthreads();
  for (int st = 512; st > 0; st >>= 1) {
    if (s < st) red[s] += red[s + st];
    __syncthreads();
  }
  if (s == 0) out[0] = (float)red[0];
  if (s == 1) out[1] = 0.f;
}

// ----------------------------------------------------------------- launch ---
extern "C" void kernel_launch(void* const* d_in, const int* in_sizes, int n_in,
                              void* d_out, int out_size, void* d_ws, size_t ws_size,
                              hipStream_t stream) {
  const int*   inputs = (const int*)  d_in[0];
  const float* z      = (const float*)d_in[1];
  const float* emb    = (const float*)d_in[2];
  const float* out_b  = (const float*)d_in[3];
  const float* h2eW   = (const float*)d_in[4];
  const float* h2eb   = (const float*)d_in[5];
  const float* Wih    = (const float*)d_in[6];
  const float* Whh    = (const float*)d_in[7];
  const float* bih    = (const float*)d_in[8];
  const float* bhh    = (const float*)d_in[9];

  char* ws8 = (char*)d_ws;
  int*    flags = (int*)ws8;                             // [0, 512) packed
  float*  Psum = (float*)(ws8 + 8192);                   // 4 KiB
  float*  Ttgt = (float*)(ws8 + 12288);                  // 4 KiB
  float*  X    = (float*)(ws8 + 24576);                  // 4 MiB
  char*   GIb  = ws8 + 24576 + (4u << 20);               // 24 MiB region
  double* GI   = (double*)GIb;
  double* E    = GI;                                     // 8 MiB overlay
  float*  candL = (float*)(GIb + (8u << 20));            // 6.11 MiB
  int*    candI = (int*)  (GIb + (8u << 20) + 6815744);  // 6.11 MiB
  double* H    = (double*)(ws8 + 24576 + (28u << 20));   // 8 MiB
  float*  out  = (float*)d_out;

  hipMemsetAsync(ws8, 0, 16384, stream);                 // flags + Psum + Ttgt

  k_gather<<<1024, 256, 0, stream>>>(inputs, emb, X);
  k_gemm_ffd<<<dim3(48, 16), 256, 0, stream>>>(X, Wih, bih, GI, 3072, KDIM);
  k_recur<<<64, 512, 0, stream>>>(z, Whh, bhh, GI, H, flags);
  k_gemm_dfd<<<dim3(16, 16), 256, 0, stream>>>(H, h2eW, h2eb, E, KDIM, KDIM);
  k_logits<<<dim3(NCH, 16), 256, 0, stream>>>(E, emb, out_b, inputs,
                                              candL, candI, Psum, Ttgt);
  k_preds<<<T_STEPS, 256, 0, stream>>>(candL, candI, out);
  k_finish<<<1, 1024, 0, stream>>>(Psum, Ttgt, out);
}

// Round 9
// 9355.036 us; speedup vs baseline: 1.5809x; 1.2826x over previous
//
#include <hip/hip_runtime.h>
#include <math.h>

#define NV      50000
#define T_STEPS 1023
#define KDIM    1024
#define NCH     782   // ceil(50000/64)
typedef unsigned long long ull;

// ws layout (bytes):
//   [0, 16384)           SA    ull[2][1024]  (seq<<32 | hi32(h))
//   [16384, 32768)       SB    ull[2][1024]  (seq<<32 | lo32(h))
//   [32768, 33280)       done  int[2][64]    (consumption acks)
//   [33280, 37376)       Psum  f32[1024]
//   [37376, 41472)       Ttgt  f32[1024]
//   [49152, +4M)         X     f32[1024*1024]
//   [49152+4M, +28M)     GI    f64[1024*3072]; after recurrence:
//                          [+0, +8M)       E f64[1024*1024]
//                          [+8M, +14.5M)   candL f32[1024*1564]
//                          [+14.5M,+21M)   candI i32[1024*1564]
//   [49152+28M, +36M)    H     f64[1024*1024]
// total ~36.05 MiB

// ---------------------------------------------------------------- gather ----
__global__ __launch_bounds__(256) void k_gather(const int* __restrict__ inputs,
                                                const float* __restrict__ emb,
                                                float* __restrict__ X) {
  const int t = blockIdx.x;      // 0..1023 (row 1023 = zero pad)
  const int tid = threadIdx.x;
  float4 v = make_float4(0.f, 0.f, 0.f, 0.f);
  if (t < T_STEPS) {
    const int tok = (t == 0) ? 0 : inputs[t];
    v = *(const float4*)&emb[(size_t)tok * KDIM + tid * 4];
  }
  *(float4*)&X[(size_t)t * KDIM + tid * 4] = v;
}

// ---------------- NT GEMM: A f32 x B f32 -> C f64, fp64 accumulate ----------
__global__ __launch_bounds__(256) void k_gemm_ffd(const float* __restrict__ A,
                                                  const float* __restrict__ B,
                                                  const float* __restrict__ bias,
                                                  double* __restrict__ C,
                                                  int N, int K) {
  __shared__ float As[32][68];
  __shared__ float Bs[32][68];
  const int tid = threadIdx.x;
  const int bx = blockIdx.x, by = blockIdx.y;
  const int lr = tid >> 2;            // 0..63
  const int lk = (tid & 3) * 8;       // 0,8,16,24
  const float* Ap = A + (size_t)(by * 64 + lr) * K + lk;
  const float* Bp = B + (size_t)(bx * 64 + lr) * K + lk;
  const int r0 = (tid >> 4) * 4;
  const int c0 = (tid & 15) * 4;
  double acc[4][4] = {};
  for (int kc = 0; kc < K; kc += 32) {
    const float4 a0 = *(const float4*)(Ap + kc);
    const float4 a1 = *(const float4*)(Ap + kc + 4);
    const float4 b0 = *(const float4*)(Bp + kc);
    const float4 b1 = *(const float4*)(Bp + kc + 4);
    __syncthreads();
    As[lk+0][lr]=a0.x; As[lk+1][lr]=a0.y; As[lk+2][lr]=a0.z; As[lk+3][lr]=a0.w;
    As[lk+4][lr]=a1.x; As[lk+5][lr]=a1.y; As[lk+6][lr]=a1.z; As[lk+7][lr]=a1.w;
    Bs[lk+0][lr]=b0.x; Bs[lk+1][lr]=b0.y; Bs[lk+2][lr]=b0.z; Bs[lk+3][lr]=b0.w;
    Bs[lk+4][lr]=b1.x; Bs[lk+5][lr]=b1.y; Bs[lk+6][lr]=b1.z; Bs[lk+7][lr]=b1.w;
    __syncthreads();
#pragma unroll
    for (int kk = 0; kk < 32; ++kk) {
      const float4 av = *(const float4*)&As[kk][r0];
      const float4 bv = *(const float4*)&Bs[kk][c0];
      const double aa[4] = {av.x, av.y, av.z, av.w};
      const double bb[4] = {bv.x, bv.y, bv.z, bv.w};
#pragma unroll
      for (int i = 0; i < 4; ++i)
#pragma unroll
        for (int j = 0; j < 4; ++j)
          acc[i][j] = fma(aa[i], bb[j], acc[i][j]);
    }
  }
  const int row = by * 64 + r0;
  const int col = bx * 64 + c0;
#pragma unroll
  for (int i = 0; i < 4; ++i)
#pragma unroll
    for (int j = 0; j < 4; ++j)
      C[(size_t)(row + i) * N + col + j] = acc[i][j] + (double)bias[col + j];
}

// ---------------- NT GEMM: A f64 x B f32 -> C f64, fp64 accumulate ----------
__global__ __launch_bounds__(256) void k_gemm_dfd(const double* __restrict__ A,
                                                  const float* __restrict__ B,
                                                  const float* __restrict__ bias,
                                                  double* __restrict__ C,
                                                  int N, int K) {
  __shared__ double As[32][68];
  __shared__ float  Bs[32][68];
  const int tid = threadIdx.x;
  const int bx = blockIdx.x, by = blockIdx.y;
  const int lr = tid >> 2;
  const int lk = (tid & 3) * 8;
  const double* Ap = A + (size_t)(by * 64 + lr) * K + lk;
  const float*  Bp = B + (size_t)(bx * 64 + lr) * K + lk;
  const int r0 = (tid >> 4) * 4;
  const int c0 = (tid & 15) * 4;
  double acc[4][4] = {};
  for (int kc = 0; kc < K; kc += 32) {
    double ar[8];
#pragma unroll
    for (int q = 0; q < 8; ++q) ar[q] = Ap[kc + q];
    const float4 b0 = *(const float4*)(Bp + kc);
    const float4 b1 = *(const float4*)(Bp + kc + 4);
    __syncthreads();
#pragma unroll
    for (int q = 0; q < 8; ++q) As[lk + q][lr] = ar[q];
    Bs[lk+0][lr]=b0.x; Bs[lk+1][lr]=b0.y; Bs[lk+2][lr]=b0.z; Bs[lk+3][lr]=b0.w;
    Bs[lk+4][lr]=b1.x; Bs[lk+5][lr]=b1.y; Bs[lk+6][lr]=b1.z; Bs[lk+7][lr]=b1.w;
    __syncthreads();
#pragma unroll
    for (int kk = 0; kk < 32; ++kk) {
      const double aa[4] = {As[kk][r0+0], As[kk][r0+1], As[kk][r0+2], As[kk][r0+3]};
      const float4 bv = *(const float4*)&Bs[kk][c0];
      const double bb[4] = {bv.x, bv.y, bv.z, bv.w};
#pragma unroll
      for (int i = 0; i < 4; ++i)
#pragma unroll
        for (int j = 0; j < 4; ++j)
          acc[i][j] = fma(aa[i], bb[j], acc[i][j]);
    }
  }
  const int row = by * 64 + r0;
  const int col = bx * 64 + c0;
#pragma unroll
  for (int i = 0; i < 4; ++i)
#pragma unroll
    for (int j = 0; j < 4; ++j)
      C[(size_t)(row + i) * N + col + j] = acc[i][j] + (double)bias[col + j];
}

// -------------------- persistent GRU recurrence (single launch) -------------
// 64 blocks x 512 threads. Wave w of block b owns h-indices {b*16+w*2, +1};
// W_hh rows in registers (fp32); fp64 dots + gates (bit-identical to the
// passing round-5 k_step).
// Sync: NO barrier, NO fences. h is published as two seq-tagged 64-bit words
// (SA = seq<<32 | hi32, SB = seq<<32 | lo32) via relaxed agent atomics;
// consumers spin on the words themselves (data == flag). Parity-2 buffers
// with consumption acks done[p][block]: a writer reusing parity p at step t
// first checks done[p][*] >= t-1 (one step of slack -> off critical path).
__global__ __launch_bounds__(512, 2) void k_recur(const float* __restrict__ z,
                                                  const float* __restrict__ Whh,
                                                  const float* __restrict__ bhh,
                                                  const double* __restrict__ GI,
                                                  double* H, ull* SA, ull* SB,
                                                  int* done) {
  __shared__ double hs[1024];
  const int tid = threadIdx.x;
  const int w = tid >> 6, l = tid & 63;
  const int ibase = blockIdx.x * 16 + w * 2;
  float wreg[6][16];
#pragma unroll
  for (int il = 0; il < 2; ++il)
#pragma unroll
    for (int g = 0; g < 3; ++g) {
      const float* wp = Whh + (size_t)(g * 1024 + ibase + il) * 1024 + l;
#pragma unroll
      for (int m = 0; m < 16; ++m) wreg[il * 3 + g][m] = wp[m * 64];
    }
  double bh[6];
#pragma unroll
  for (int il = 0; il < 2; ++il)
#pragma unroll
    for (int g = 0; g < 3; ++g) bh[il * 3 + g] = (double)bhh[g * 1024 + ibase + il];

  // h_{-1} = z; GI row 0 preloaded
  hs[tid]       = (double)z[tid];
  hs[tid + 512] = (double)z[tid + 512];
  double gi[6];
#pragma unroll
  for (int il = 0; il < 2; ++il)
#pragma unroll
    for (int g = 0; g < 3; ++g) gi[il * 3 + g] = GI[g * 1024 + ibase + il];
  __syncthreads();

  for (int t = 0; t < T_STEPS; ++t) {
    const bool more = (t + 1 < T_STEPS);
    const int p = t & 1;
    // pre-issue backpressure-ack load (wave 0); latency hides under matvec
    const bool gate = more && (t >= 2);
    int dv = 0x7FFFFFFF;
    if (gate && tid < 64)
      dv = __hip_atomic_load(done + p * 64 + tid,
                             __ATOMIC_RELAXED, __HIP_MEMORY_SCOPE_AGENT);
    // matvec
    double s[6] = {0.0, 0.0, 0.0, 0.0, 0.0, 0.0};
#pragma unroll
    for (int m = 0; m < 16; ++m) {
      const double hv = hs[l + 64 * m];
#pragma unroll
      for (int rr = 0; rr < 6; ++rr) s[rr] = fma((double)wreg[rr][m], hv, s[rr]);
    }
#pragma unroll
    for (int rr = 0; rr < 6; ++rr) {
      double v = s[rr];
#pragma unroll
      for (int mk = 32; mk >= 1; mk >>= 1) v += __shfl_xor(v, mk, 64);
      s[rr] = v;
    }
    // gates (lane 0 -> il=0, lane 1 -> il=1); hn kept in register
    double hn = 0.0;
    if (l < 2) {
      const int il = l;
      const double r  = 1.0 / (1.0 + exp(-(gi[il * 3 + 0] + s[il * 3 + 0] + bh[il * 3 + 0])));
      const double zg = 1.0 / (1.0 + exp(-(gi[il * 3 + 1] + s[il * 3 + 1] + bh[il * 3 + 1])));
      const double n  = tanh(gi[il * 3 + 2] + r * (s[il * 3 + 2] + bh[il * 3 + 2]));
      hn = (1.0 - zg) * n + zg * hs[ibase + l];
    }
    // prefetch GI row t+1 (independent of h)
    double gin[6] = {0.0, 0.0, 0.0, 0.0, 0.0, 0.0};
    if (more) {
      const double* gp = GI + (size_t)(t + 1) * 3072;
#pragma unroll
      for (int il = 0; il < 2; ++il)
#pragma unroll
        for (int g = 0; g < 3; ++g) gin[il * 3 + g] = gp[g * 1024 + ibase + il];
    }
    // backpressure: parity-p slots must have been consumed for step t-2
    if (gate && tid < 64) {
      while (!__all(dv >= t - 1)) {
        __builtin_amdgcn_s_sleep(1);
        dv = __hip_atomic_load(done + p * 64 + tid,
                               __ATOMIC_RELAXED, __HIP_MEMORY_SCOPE_AGENT);
      }
    }
    __syncthreads();
    // publish
    if (l < 2) {
      const int gidx = ibase + l;
      __hip_atomic_store(H + (size_t)t * 1024 + gidx, hn,
                         __ATOMIC_RELAXED, __HIP_MEMORY_SCOPE_AGENT);
      if (more) {
        const ull hb  = (ull)__double_as_longlong(hn);
        const ull tag = ((ull)(t + 1)) << 32;
        __hip_atomic_store(SA + p * 1024 + gidx, tag | (hb >> 32),
                           __ATOMIC_RELAXED, __HIP_MEMORY_SCOPE_AGENT);
        __hip_atomic_store(SB + p * 1024 + gidx, tag | (hb & 0xFFFFFFFFull),
                           __ATOMIC_RELAXED, __HIP_MEMORY_SCOPE_AGENT);
      }
    }
    if (more) {
      // consume: spin on the seq-tagged words themselves
      const ull want = (ull)(t + 1);
      ull a0, b0, a1, b1;
      while (true) {
        a0 = __hip_atomic_load(SA + p * 1024 + tid,
                               __ATOMIC_RELAXED, __HIP_MEMORY_SCOPE_AGENT);
        b0 = __hip_atomic_load(SB + p * 1024 + tid,
                               __ATOMIC_RELAXED, __HIP_MEMORY_SCOPE_AGENT);
        if ((a0 >> 32) >= want && (b0 >> 32) >= want) break;
        __builtin_amdgcn_s_sleep(1);
      }
      while (true) {
        a1 = __hip_atomic_load(SA + p * 1024 + tid + 512,
                               __ATOMIC_RELAXED, __HIP_MEMORY_SCOPE_AGENT);
        b1 = __hip_atomic_load(SB + p * 1024 + tid + 512,
                               __ATOMIC_RELAXED, __HIP_MEMORY_SCOPE_AGENT);
        if ((a1 >> 32) >= want && (b1 >> 32) >= want) break;
        __builtin_amdgcn_s_sleep(1);
      }
      hs[tid]       = __longlong_as_double((long long)
                        (((a0 & 0xFFFFFFFFull) << 32) | (b0 & 0xFFFFFFFFull)));
      hs[tid + 512] = __longlong_as_double((long long)
                        (((a1 & 0xFFFFFFFFull) << 32) | (b1 & 0xFFFFFFFFull)));
      __syncthreads();
      // ack consumption of parity-p data of step t
      if (tid == 0)
        __hip_atomic_store(done + p * 64 + blockIdx.x, t + 1,
                           __ATOMIC_RELAXED, __HIP_MEMORY_SCOPE_AGENT);
#pragma unroll
      for (int q = 0; q < 6; ++q) gi[q] = gin[q];
    }
  }
}

// ------- logits GEMM (f64) + per-chunk fp32 top-2 candidates + loss stats ---
__global__ __launch_bounds__(256) void k_logits(const double* __restrict__ E,
                                                const float* __restrict__ emb,
                                                const float* __restrict__ out_b,
                                                const int* __restrict__ inputs,
                                                float* __restrict__ candL,
                                                int* __restrict__ candI,
                                                float* __restrict__ Psum,
                                                float* __restrict__ Ttgt) {
  __shared__ double As[32][68];
  __shared__ float  Bs[32][68];
  const int tid = threadIdx.x;
  const int bx = blockIdx.x, by = blockIdx.y;
  const int lr = tid >> 2;
  const int lk = (tid & 3) * 8;
  const int brow = bx * 64 + lr;
  const double* Ap = E + (size_t)(by * 64 + lr) * KDIM + lk;
  const float*  Bp = emb + (size_t)brow * KDIM + lk;
  const bool bvalid = (brow < NV);
  const int r0 = (tid >> 4) * 4;
  const int c0 = (tid & 15) * 4;
  double acc[4][4] = {};
  for (int kc = 0; kc < KDIM; kc += 32) {
    double ar[8];
#pragma unroll
    for (int q = 0; q < 8; ++q) ar[q] = Ap[kc + q];
    float4 b0 = make_float4(0.f, 0.f, 0.f, 0.f);
    float4 b1 = make_float4(0.f, 0.f, 0.f, 0.f);
    if (bvalid) { b0 = *(const float4*)(Bp + kc); b1 = *(const float4*)(Bp + kc + 4); }
    __syncthreads();
#pragma unroll
    for (int q = 0; q < 8; ++q) As[lk + q][lr] = ar[q];
    Bs[lk+0][lr]=b0.x; Bs[lk+1][lr]=b0.y; Bs[lk+2][lr]=b0.z; Bs[lk+3][lr]=b0.w;
    Bs[lk+4][lr]=b1.x; Bs[lk+5][lr]=b1.y; Bs[lk+6][lr]=b1.z; Bs[lk+7][lr]=b1.w;
    __syncthreads();
#pragma unroll
    for (int kk = 0; kk < 32; ++kk) {
      const double aa[4] = {As[kk][r0+0], As[kk][r0+1], As[kk][r0+2], As[kk][r0+3]};
      const float4 bv = *(const float4*)&Bs[kk][c0];
      const double bb[4] = {bv.x, bv.y, bv.z, bv.w};
#pragma unroll
      for (int i = 0; i < 4; ++i)
#pragma unroll
        for (int j = 0; j < 4; ++j)
          acc[i][j] = fma(aa[i], bb[j], acc[i][j]);
    }
  }
  const int colb = bx * 64 + c0;
#pragma unroll
  for (int i = 0; i < 4; ++i) {
    const int s = by * 64 + r0 + i;
    const bool valid = (s < T_STEPS);
    const int tgt = valid ? inputs[s + 1] : -1;
    float L1 = -3e38f, L2 = -3e38f;
    int   i1 = 0x7FFFFFFF, i2 = 0x7FFFFFFF;
    float se = 0.f, tv = -INFINITY;
#pragma unroll
    for (int j = 0; j < 4; ++j) {
      const int v = colb + j;
      if (v < NV) {
        const double lgd = acc[i][j] + (double)out_b[v];
        const float L = (float)lgd;           // np's fp32 logit (bit-matched)
        se += expf((float)(lgd - 0.01));
        if (v == tgt) tv = (float)lgd;
        if (L > L1 || (L == L1 && v < i1)) { L2 = L1; i2 = i1; L1 = L; i1 = v; }
        else if (L > L2 || (L == L2 && v < i2)) { L2 = L; i2 = v; }
      }
    }
#pragma unroll
    for (int mk = 1; mk <= 8; mk <<= 1) {
      const float oL1 = __shfl_xor(L1, mk, 64); const int oi1 = __shfl_xor(i1, mk, 64);
      const float oL2 = __shfl_xor(L2, mk, 64); const int oi2 = __shfl_xor(i2, mk, 64);
      if (oL1 > L1 || (oL1 == L1 && oi1 < i1)) { L2 = L1; i2 = i1; L1 = oL1; i1 = oi1; }
      else if (oL1 > L2 || (oL1 == L2 && oi1 < i2)) { L2 = oL1; i2 = oi1; }
      if (oL2 > L1 || (oL2 == L1 && oi2 < i1)) { L2 = L1; i2 = i1; L1 = oL2; i1 = oi2; }
      else if (oL2 > L2 || (oL2 == L2 && oi2 < i2)) { L2 = oL2; i2 = oi2; }
      se += __shfl_xor(se, mk, 64);
      tv = fmaxf(tv, __shfl_xor(tv, mk, 64));
    }
    if (((tid & 15) == 0) && valid) {
      const size_t p = (size_t)s * (2 * NCH) + 2 * bx;
      candL[p] = L1;     candI[p] = i1;
      candL[p + 1] = L2; candI[p + 1] = i2;
      atomicAdd(&Psum[s], se);
      if (tv > -1e30f) Ttgt[s] = tv;
    }
  }
}

// --------- preds: np-faithful fp32 log_softmax quantized argmax -------------
__global__ __launch_bounds__(256) void k_preds(const float* __restrict__ candL,
                                               const int* __restrict__ candI,
                                               float* __restrict__ out) {
  __shared__ float sL[256];
  __shared__ int   sI[256];
  const int s = blockIdx.x;        // 0..1022
  const int tid = threadIdx.x;
  const int n = 2 * NCH;           // 1564
  const size_t base = (size_t)s * n;
  float m = -3e38f;
  for (int c = tid; c < n; c += 256) m = fmaxf(m, candL[base + c]);
  sL[tid] = m; __syncthreads();
  for (int st = 128; st > 0; st >>= 1) {
    if (tid < st) sL[tid] = fmaxf(sL[tid], sL[tid + st]);
    __syncthreads();
  }
  const float Lmax = sL[0];
  __syncthreads();
  float bq = -3e38f; int bi = 0x7FFFFFFF;
  for (int c = tid; c < n; c += 256) {
    const float L = candL[base + c];
    const int   v = candI[base + c];
    const float d = L - Lmax;              // Sterbenz-exact
    const float q = d - 10.8125f;          // fp32 bucket quantization
    if (q > bq || (q == bq && v < bi)) { bq = q; bi = v; }
  }
  sL[tid] = bq; sI[tid] = bi; __syncthreads();
  for (int st = 128; st > 0; st >>= 1) {
    if (tid < st) {
      if (sL[tid + st] > sL[tid] ||
          (sL[tid + st] == sL[tid] && sI[tid + st] < sI[tid])) {
        sL[tid] = sL[tid + st]; sI[tid] = sI[tid + st];
      }
    }
    __syncthreads();
  }
  if (tid == 0) out[2 + s] = (float)sI[0];
}

// ------------------------------------------------ final loss ----------------
__global__ __launch_bounds__(1024) void k_finish(const float* __restrict__ Psum,
                                                 const float* __restrict__ Ttgt,
                                                 float* __restrict__ out) {
  __shared__ double red[1024];
  const int s = threadIdx.x;
  double ls = 0.0;
  if (s < T_STEPS) ls = 0.01 + log((double)Psum[s]) - (double)Ttgt[s];
  red[s] = ls;
  __syncthreads();
  for (int st = 512; st > 0; st >>= 1) {
    if (s < st) red[s] += red[s + st];
    __syncthreads();
  }
  if (s == 0) out[0] = (float)red[0];
  if (s == 1) out[1] = 0.f;
}

// ----------------------------------------------------------------- launch ---
extern "C" void kernel_launch(void* const* d_in, const int* in_sizes, int n_in,
                              void* d_out, int out_size, void* d_ws, size_t ws_size,
                              hipStream_t stream) {
  const int*   inputs = (const int*)  d_in[0];
  const float* z      = (const float*)d_in[1];
  const float* emb    = (const float*)d_in[2];
  const float* out_b  = (const float*)d_in[3];
  const float* h2eW   = (const float*)d_in[4];
  const float* h2eb   = (const float*)d_in[5];
  const float* Wih    = (const float*)d_in[6];
  const float* Whh    = (const float*)d_in[7];
  const float* bih    = (const float*)d_in[8];
  const float* bhh    = (const float*)d_in[9];

  char* ws8 = (char*)d_ws;
  ull*    SA   = (ull*)ws8;                              // [0, 16K)
  ull*    SB   = (ull*)(ws8 + 16384);                    // [16K, 32K)
  int*    done = (int*)(ws8 + 32768);                    // [32K, +512)
  float*  Psum = (float*)(ws8 + 33280);                  // 4 KiB
  float*  Ttgt = (float*)(ws8 + 37376);                  // 4 KiB
  float*  X    = (float*)(ws8 + 49152);                  // 4 MiB
  char*   GIb  = ws8 + 49152 + (4u << 20);               // 24 MiB region
  double* GI   = (double*)GIb;
  double* E    = GI;                                     // 8 MiB overlay
  float*  candL = (float*)(GIb + (8u << 20));            // 6.11 MiB
  int*    candI = (int*)  (GIb + (8u << 20) + 6815744);  // 6.11 MiB
  double* H    = (double*)(ws8 + 49152 + (28u << 20));   // 8 MiB
  float*  out  = (float*)d_out;

  hipMemsetAsync(ws8, 0, 49152, stream);   // SA + SB + done + Psum + Ttgt

  k_gather<<<1024, 256, 0, stream>>>(inputs, emb, X);
  k_gemm_ffd<<<dim3(48, 16), 256, 0, stream>>>(X, Wih, bih, GI, 3072, KDIM);
  k_recur<<<64, 512, 0, stream>>>(z, Whh, bhh, GI, H, SA, SB, done);
  k_gemm_dfd<<<dim3(16, 16), 256, 0, stream>>>(H, h2eW, h2eb, E, KDIM, KDIM);
  k_logits<<<dim3(NCH, 16), 256, 0, stream>>>(E, emb, out_b, inputs,
                                              candL, candI, Psum, Ttgt);
  k_preds<<<T_STEPS, 256, 0, stream>>>(candL, candI, out);
  k_finish<<<1, 1024, 0, stream>>>(Psum, Ttgt, out);
}

// Round 10
// 9260.197 us; speedup vs baseline: 1.5971x; 1.0102x over previous
//
#include <hip/hip_runtime.h>
#include <math.h>

#define NV      50000
#define T_STEPS 1023
#define KDIM    1024
#define NCH     391   // ceil(50000/128) logits chunks
typedef unsigned long long ull;

// ws layout (bytes):
//   [0, 32768)           SA    ull[4][1024]  (seq<<32 | hi32(h))
//   [32768, 65536)       SB    ull[4][1024]  (seq<<32 | lo32(h))
//   [65536, 66560)       done  int[4][64]    (consumption acks)
//   [66560, 70656)       Psum  f32[1024]
//   [70656, 74752)       Ttgt  f32[1024]
//   [81920, +4M)         X     f32[1024*1024]
//   [81920+4M, +28M)     GI    f64[1024*3072]; after recurrence:
//                          [+0, +8M)         E f64[1024*1024]
//                          [+8M, +11.06M)    candL f32[1024*782]
//                          [+11.06M, +14.1M) candI i32[1024*782]
//   [81920+28M, +36M)    H     f64[1024*1024]
// total ~36.08 MiB

// ---------------------------------------------------------------- gather ----
__global__ __launch_bounds__(256) void k_gather(const int* __restrict__ inputs,
                                                const float* __restrict__ emb,
                                                float* __restrict__ X) {
  const int t = blockIdx.x;      // 0..1023 (row 1023 = zero pad)
  const int tid = threadIdx.x;
  float4 v = make_float4(0.f, 0.f, 0.f, 0.f);
  if (t < T_STEPS) {
    const int tok = (t == 0) ? 0 : inputs[t];
    v = *(const float4*)&emb[(size_t)tok * KDIM + tid * 4];
  }
  *(float4*)&X[(size_t)t * KDIM + tid * 4] = v;
}

// ---------------- NT GEMM: A f32 x B f32 -> C f64, fp64 accumulate ----------
__global__ __launch_bounds__(256) void k_gemm_ffd(const float* __restrict__ A,
                                                  const float* __restrict__ B,
                                                  const float* __restrict__ bias,
                                                  double* __restrict__ C,
                                                  int N, int K) {
  __shared__ float As[32][68];
  __shared__ float Bs[32][68];
  const int tid = threadIdx.x;
  const int bx = blockIdx.x, by = blockIdx.y;
  const int lr = tid >> 2;            // 0..63
  const int lk = (tid & 3) * 8;       // 0,8,16,24
  const float* Ap = A + (size_t)(by * 64 + lr) * K + lk;
  const float* Bp = B + (size_t)(bx * 64 + lr) * K + lk;
  const int r0 = (tid >> 4) * 4;
  const int c0 = (tid & 15) * 4;
  double acc[4][4] = {};
  for (int kc = 0; kc < K; kc += 32) {
    const float4 a0 = *(const float4*)(Ap + kc);
    const float4 a1 = *(const float4*)(Ap + kc + 4);
    const float4 b0 = *(const float4*)(Bp + kc);
    const float4 b1 = *(const float4*)(Bp + kc + 4);
    __syncthreads();
    As[lk+0][lr]=a0.x; As[lk+1][lr]=a0.y; As[lk+2][lr]=a0.z; As[lk+3][lr]=a0.w;
    As[lk+4][lr]=a1.x; As[lk+5][lr]=a1.y; As[lk+6][lr]=a1.z; As[lk+7][lr]=a1.w;
    Bs[lk+0][lr]=b0.x; Bs[lk+1][lr]=b0.y; Bs[lk+2][lr]=b0.z; Bs[lk+3][lr]=b0.w;
    Bs[lk+4][lr]=b1.x; Bs[lk+5][lr]=b1.y; Bs[lk+6][lr]=b1.z; Bs[lk+7][lr]=b1.w;
    __syncthreads();
#pragma unroll
    for (int kk = 0; kk < 32; ++kk) {
      const float4 av = *(const float4*)&As[kk][r0];
      const float4 bv = *(const float4*)&Bs[kk][c0];
      const double aa[4] = {av.x, av.y, av.z, av.w};
      const double bb[4] = {bv.x, bv.y, bv.z, bv.w};
#pragma unroll
      for (int i = 0; i < 4; ++i)
#pragma unroll
        for (int j = 0; j < 4; ++j)
          acc[i][j] = fma(aa[i], bb[j], acc[i][j]);
    }
  }
  const int row = by * 64 + r0;
  const int col = bx * 64 + c0;
#pragma unroll
  for (int i = 0; i < 4; ++i)
#pragma unroll
    for (int j = 0; j < 4; ++j)
      C[(size_t)(row + i) * N + col + j] = acc[i][j] + (double)bias[col + j];
}

// ---------------- NT GEMM: A f64 x B f32 -> C f64, fp64 accumulate ----------
__global__ __launch_bounds__(256) void k_gemm_dfd(const double* __restrict__ A,
                                                  const float* __restrict__ B,
                                                  const float* __restrict__ bias,
                                                  double* __restrict__ C,
                                                  int N, int K) {
  __shared__ double As[32][68];
  __shared__ float  Bs[32][68];
  const int tid = threadIdx.x;
  const int bx = blockIdx.x, by = blockIdx.y;
  const int lr = tid >> 2;
  const int lk = (tid & 3) * 8;
  const double* Ap = A + (size_t)(by * 64 + lr) * K + lk;
  const float*  Bp = B + (size_t)(bx * 64 + lr) * K + lk;
  const int r0 = (tid >> 4) * 4;
  const int c0 = (tid & 15) * 4;
  double acc[4][4] = {};
  for (int kc = 0; kc < K; kc += 32) {
    double ar[8];
#pragma unroll
    for (int q = 0; q < 8; ++q) ar[q] = Ap[kc + q];
    const float4 b0 = *(const float4*)(Bp + kc);
    const float4 b1 = *(const float4*)(Bp + kc + 4);
    __syncthreads();
#pragma unroll
    for (int q = 0; q < 8; ++q) As[lk + q][lr] = ar[q];
    Bs[lk+0][lr]=b0.x; Bs[lk+1][lr]=b0.y; Bs[lk+2][lr]=b0.z; Bs[lk+3][lr]=b0.w;
    Bs[lk+4][lr]=b1.x; Bs[lk+5][lr]=b1.y; Bs[lk+6][lr]=b1.z; Bs[lk+7][lr]=b1.w;
    __syncthreads();
#pragma unroll
    for (int kk = 0; kk < 32; ++kk) {
      const double aa[4] = {As[kk][r0+0], As[kk][r0+1], As[kk][r0+2], As[kk][r0+3]};
      const float4 bv = *(const float4*)&Bs[kk][c0];
      const double bb[4] = {bv.x, bv.y, bv.z, bv.w};
#pragma unroll
      for (int i = 0; i < 4; ++i)
#pragma unroll
        for (int j = 0; j < 4; ++j)
          acc[i][j] = fma(aa[i], bb[j], acc[i][j]);
    }
  }
  const int row = by * 64 + r0;
  const int col = bx * 64 + c0;
#pragma unroll
  for (int i = 0; i < 4; ++i)
#pragma unroll
    for (int j = 0; j < 4; ++j)
      C[(size_t)(row + i) * N + col + j] = acc[i][j] + (double)bias[col + j];
}

// -------------------- persistent GRU recurrence (single launch) -------------
// 64 blocks x 512 threads. Wave w of block b owns h-indices {b*16+w*2, +1};
// W_hh rows in registers (fp32); fp64 dots + gates (bit-identical to the
// passing round-5 k_step).
// Sync: data-as-flag, relaxed agent atomics only, NO fences. Ring-4 parity
// (ack slack = 3 steps, backpressure gate never binds). Merged 4-word spin
// (one LLC latency per poll round). H written with PLAIN stores (consumed
// by a later kernel across a dispatch boundary only).
__global__ __launch_bounds__(512, 2) void k_recur(const float* __restrict__ z,
                                                  const float* __restrict__ Whh,
                                                  const float* __restrict__ bhh,
                                                  const double* __restrict__ GI,
                                                  double* __restrict__ H,
                                                  ull* SA, ull* SB, int* done) {
  __shared__ double hs[1024];
  const int tid = threadIdx.x;
  const int w = tid >> 6, l = tid & 63;
  const int ibase = blockIdx.x * 16 + w * 2;
  float wreg[6][16];
#pragma unroll
  for (int il = 0; il < 2; ++il)
#pragma unroll
    for (int g = 0; g < 3; ++g) {
      const float* wp = Whh + (size_t)(g * 1024 + ibase + il) * 1024 + l;
#pragma unroll
      for (int m = 0; m < 16; ++m) wreg[il * 3 + g][m] = wp[m * 64];
    }
  double bh[6];
#pragma unroll
  for (int il = 0; il < 2; ++il)
#pragma unroll
    for (int g = 0; g < 3; ++g) bh[il * 3 + g] = (double)bhh[g * 1024 + ibase + il];

  // h_{-1} = z; GI row 0 preloaded
  hs[tid]       = (double)z[tid];
  hs[tid + 512] = (double)z[tid + 512];
  double gi[6];
#pragma unroll
  for (int il = 0; il < 2; ++il)
#pragma unroll
    for (int g = 0; g < 3; ++g) gi[il * 3 + g] = GI[g * 1024 + ibase + il];
  __syncthreads();

  for (int t = 0; t < T_STEPS; ++t) {
    const bool more = (t + 1 < T_STEPS);
    const int p = t & 3;
    // pre-issue backpressure-ack load (wave 0); latency hides under matvec
    const bool gate = more && (t >= 4);
    int dv = 0x7FFFFFFF;
    if (gate && tid < 64)
      dv = __hip_atomic_load(done + p * 64 + tid,
                             __ATOMIC_RELAXED, __HIP_MEMORY_SCOPE_AGENT);
    // matvec
    double s[6] = {0.0, 0.0, 0.0, 0.0, 0.0, 0.0};
#pragma unroll
    for (int m = 0; m < 16; ++m) {
      const double hv = hs[l + 64 * m];
#pragma unroll
      for (int rr = 0; rr < 6; ++rr) s[rr] = fma((double)wreg[rr][m], hv, s[rr]);
    }
#pragma unroll
    for (int rr = 0; rr < 6; ++rr) {
      double v = s[rr];
#pragma unroll
      for (int mk = 32; mk >= 1; mk >>= 1) v += __shfl_xor(v, mk, 64);
      s[rr] = v;
    }
    // gates (lane 0 -> il=0, lane 1 -> il=1); hn kept in register
    double hn = 0.0;
    if (l < 2) {
      const int il = l;
      const double r  = 1.0 / (1.0 + exp(-(gi[il * 3 + 0] + s[il * 3 + 0] + bh[il * 3 + 0])));
      const double zg = 1.0 / (1.0 + exp(-(gi[il * 3 + 1] + s[il * 3 + 1] + bh[il * 3 + 1])));
      const double n  = tanh(gi[il * 3 + 2] + r * (s[il * 3 + 2] + bh[il * 3 + 2]));
      hn = (1.0 - zg) * n + zg * hs[ibase + l];
    }
    // prefetch GI row t+1 (independent of h)
    double gin[6] = {0.0, 0.0, 0.0, 0.0, 0.0, 0.0};
    if (more) {
      const double* gp = GI + (size_t)(t + 1) * 3072;
#pragma unroll
      for (int il = 0; il < 2; ++il)
#pragma unroll
        for (int g = 0; g < 3; ++g) gin[il * 3 + g] = gp[g * 1024 + ibase + il];
    }
    // backpressure: ring slot p must have been consumed at step t-4
    if (gate && tid < 64) {
      while (!__all(dv >= t - 3)) {
        __builtin_amdgcn_s_sleep(1);
        dv = __hip_atomic_load(done + p * 64 + tid,
                               __ATOMIC_RELAXED, __HIP_MEMORY_SCOPE_AGENT);
      }
    }
    __syncthreads();
    // publish
    if (l < 2) {
      const int gidx = ibase + l;
      H[(size_t)t * 1024 + gidx] = hn;          // plain store (later kernel)
      if (more) {
        const ull hb  = (ull)__double_as_longlong(hn);
        const ull tag = ((ull)(t + 1)) << 32;
        __hip_atomic_store(SA + p * 1024 + gidx, tag | (hb >> 32),
                           __ATOMIC_RELAXED, __HIP_MEMORY_SCOPE_AGENT);
        __hip_atomic_store(SB + p * 1024 + gidx, tag | (hb & 0xFFFFFFFFull),
                           __ATOMIC_RELAXED, __HIP_MEMORY_SCOPE_AGENT);
      }
    }
    if (more) {
      // merged spin: all 4 words polled per round (single LLC latency)
      const ull want = (ull)(t + 1);
      ull a0, b0, a1, b1;
      while (true) {
        a0 = __hip_atomic_load(SA + p * 1024 + tid,
                               __ATOMIC_RELAXED, __HIP_MEMORY_SCOPE_AGENT);
        b0 = __hip_atomic_load(SB + p * 1024 + tid,
                               __ATOMIC_RELAXED, __HIP_MEMORY_SCOPE_AGENT);
        a1 = __hip_atomic_load(SA + p * 1024 + tid + 512,
                               __ATOMIC_RELAXED, __HIP_MEMORY_SCOPE_AGENT);
        b1 = __hip_atomic_load(SB + p * 1024 + tid + 512,
                               __ATOMIC_RELAXED, __HIP_MEMORY_SCOPE_AGENT);
        if ((a0 >> 32) >= want && (b0 >> 32) >= want &&
            (a1 >> 32) >= want && (b1 >> 32) >= want) break;
        __builtin_amdgcn_s_sleep(1);
      }
      hs[tid]       = __longlong_as_double((long long)
                        (((a0 & 0xFFFFFFFFull) << 32) | (b0 & 0xFFFFFFFFull)));
      hs[tid + 512] = __longlong_as_double((long long)
                        (((a1 & 0xFFFFFFFFull) << 32) | (b1 & 0xFFFFFFFFull)));
      __syncthreads();
      // ack consumption of ring slot p (all threads captured)
      if (tid == 0)
        __hip_atomic_store(done + p * 64 + blockIdx.x, t + 1,
                           __ATOMIC_RELAXED, __HIP_MEMORY_SCOPE_AGENT);
#pragma unroll
      for (int q = 0; q < 6; ++q) gi[q] = gin[q];
    }
  }
}

// ------- logits GEMM (f64, 64x128 tile, 4x8 acc) + top-2 + loss stats -------
__global__ __launch_bounds__(256) void k_logits(const double* __restrict__ E,
                                                const float* __restrict__ emb,
                                                const float* __restrict__ out_b,
                                                const int* __restrict__ inputs,
                                                float* __restrict__ candL,
                                                int* __restrict__ candI,
                                                float* __restrict__ Psum,
                                                float* __restrict__ Ttgt) {
  __shared__ double As[32][66];
  __shared__ float  Bs[32][132];
  const int tid = threadIdx.x;
  const int bx = blockIdx.x, by = blockIdx.y;
  // A loader: 64 rows x 32 k, 8 f64/thread
  const int lr = tid >> 2;            // 0..63
  const int lk = (tid & 3) * 8;       // 0,8,16,24
  const double* Ap = E + (size_t)(by * 64 + lr) * KDIM + lk;
  // B loader: 128 rows x 32 k, 16 f32/thread
  const int bcol = tid >> 1;          // 0..127
  const int bk   = (tid & 1) * 16;    // 0,16
  const int brow = bx * 128 + bcol;
  const float* Bp = emb + (size_t)brow * KDIM + bk;
  const bool bvalid = (brow < NV);
  const int r0 = (tid >> 4) * 4;      // 0..60
  const int c0 = (tid & 15) * 8;      // 0..120
  double acc[4][8] = {};
  for (int kc = 0; kc < KDIM; kc += 32) {
    double ar[8];
#pragma unroll
    for (int q = 0; q < 8; ++q) ar[q] = Ap[kc + q];
    float4 br[4];
#pragma unroll
    for (int q = 0; q < 4; ++q)
      br[q] = bvalid ? *(const float4*)(Bp + kc + q * 4)
                     : make_float4(0.f, 0.f, 0.f, 0.f);
    __syncthreads();
#pragma unroll
    for (int q = 0; q < 8; ++q) As[lk + q][lr] = ar[q];
#pragma unroll
    for (int q = 0; q < 4; ++q) {
      Bs[bk + q * 4 + 0][bcol] = br[q].x;
      Bs[bk + q * 4 + 1][bcol] = br[q].y;
      Bs[bk + q * 4 + 2][bcol] = br[q].z;
      Bs[bk + q * 4 + 3][bcol] = br[q].w;
    }
    __syncthreads();
#pragma unroll
    for (int kk = 0; kk < 32; ++kk) {
      const double aa[4] = {As[kk][r0+0], As[kk][r0+1], As[kk][r0+2], As[kk][r0+3]};
      const float4 bv0 = *(const float4*)&Bs[kk][c0];
      const float4 bv1 = *(const float4*)&Bs[kk][c0 + 4];
      const double bb[8] = {bv0.x, bv0.y, bv0.z, bv0.w,
                            bv1.x, bv1.y, bv1.z, bv1.w};
#pragma unroll
      for (int i = 0; i < 4; ++i)
#pragma unroll
        for (int j = 0; j < 8; ++j)
          acc[i][j] = fma(aa[i], bb[j], acc[i][j]);
    }
  }
  const int colb = bx * 128 + c0;
#pragma unroll
  for (int i = 0; i < 4; ++i) {
    const int s = by * 64 + r0 + i;
    const bool valid = (s < T_STEPS);
    const int tgt = valid ? inputs[s + 1] : -1;
    float L1 = -3e38f, L2 = -3e38f;
    int   i1 = 0x7FFFFFFF, i2 = 0x7FFFFFFF;
    float se = 0.f, tv = -INFINITY;
#pragma unroll
    for (int j = 0; j < 8; ++j) {
      const int v = colb + j;
      if (v < NV) {
        const double lgd = acc[i][j] + (double)out_b[v];
        const float L = (float)lgd;           // np's fp32 logit (bit-matched)
        se += expf((float)(lgd - 0.01));
        if (v == tgt) tv = (float)lgd;
        if (L > L1 || (L == L1 && v < i1)) { L2 = L1; i2 = i1; L1 = L; i1 = v; }
        else if (L > L2 || (L == L2 && v < i2)) { L2 = L; i2 = v; }
      }
    }
#pragma unroll
    for (int mk = 1; mk <= 8; mk <<= 1) {
      const float oL1 = __shfl_xor(L1, mk, 64); const int oi1 = __shfl_xor(i1, mk, 64);
      const float oL2 = __shfl_xor(L2, mk, 64); const int oi2 = __shfl_xor(i2, mk, 64);
      if (oL1 > L1 || (oL1 == L1 && oi1 < i1)) { L2 = L1; i2 = i1; L1 = oL1; i1 = oi1; }
      else if (oL1 > L2 || (oL1 == L2 && oi1 < i2)) { L2 = oL1; i2 = oi1; }
      if (oL2 > L1 || (oL2 == L1 && oi2 < i1)) { L2 = L1; i2 = i1; L1 = oL2; i1 = oi2; }
      else if (oL2 > L2 || (oL2 == L2 && oi2 < i2)) { L2 = oL2; i2 = oi2; }
      se += __shfl_xor(se, mk, 64);
      tv = fmaxf(tv, __shfl_xor(tv, mk, 64));
    }
    if (((tid & 15) == 0) && valid) {
      const size_t p = (size_t)s * (2 * NCH) + 2 * bx;
      candL[p] = L1;     candI[p] = i1;
      candL[p + 1] = L2; candI[p + 1] = i2;
      atomicAdd(&Psum[s], se);
      if (tv > -1e30f) Ttgt[s] = tv;
    }
  }
}

// --------- preds: np-faithful fp32 log_softmax quantized argmax -------------
__global__ __launch_bounds__(256) void k_preds(const float* __restrict__ candL,
                                               const int* __restrict__ candI,
                                               float* __restrict__ out) {
  __shared__ float sL[256];
  __shared__ int   sI[256];
  const int s = blockIdx.x;        // 0..1022
  const int tid = threadIdx.x;
  const int n = 2 * NCH;           // 782
  const size_t base = (size_t)s * n;
  float m = -3e38f;
  for (int c = tid; c < n; c += 256) m = fmaxf(m, candL[base + c]);
  sL[tid] = m; __syncthreads();
  for (int st = 128; st > 0; st >>= 1) {
    if (tid < st) sL[tid] = fmaxf(sL[tid], sL[tid + st]);
    __syncthreads();
  }
  const float Lmax = sL[0];
  __syncthreads();
  float bq = -3e38f; int bi = 0x7FFFFFFF;
  for (int c = tid; c < n; c += 256) {
    const float L = candL[base + c];
    const int   v = candI[base + c];
    const float d = L - Lmax;              // Sterbenz-exact
    const float q = d - 10.8125f;          // fp32 bucket quantization
    if (q > bq || (q == bq && v < bi)) { bq = q; bi = v; }
  }
  sL[tid] = bq; sI[tid] = bi; __syncthreads();
  for (int st = 128; st > 0; st >>= 1) {
    if (tid < st) {
      if (sL[tid + st] > sL[tid] ||
          (sL[tid + st] == sL[tid] && sI[tid + st] < sI[tid])) {
        sL[tid] = sL[tid + st]; sI[tid] = sI[tid + st];
      }
    }
    __syncthreads();
  }
  if (tid == 0) out[2 + s] = (float)sI[0];
}

// ------------------------------------------------ final loss ----------------
__global__ __launch_bounds__(1024) void k_finish(const float* __restrict__ Psum,
                                                 const float* __restrict__ Ttgt,
                                                 float* __restrict__ out) {
  __shared__ double red[1024];
  const int s = threadIdx.x;
  double ls = 0.0;
  if (s < T_STEPS) ls = 0.01 + log((double)Psum[s]) - (double)Ttgt[s];
  red[s] = ls;
  __syncthreads();
  for (int st = 512; st > 0; st >>= 1) {
    if (s < st) red[s] += red[s + st];
    __syncthreads();
  }
  if (s == 0) out[0] = (float)red[0];
  if (s == 1) out[1] = 0.f;
}

// ----------------------------------------------------------------- launch ---
extern "C" void kernel_launch(void* const* d_in, const int* in_sizes, int n_in,
                              void* d_out, int out_size, void* d_ws, size_t ws_size,
                              hipStream_t stream) {
  const int*   inputs = (const int*)  d_in[0];
  const float* z      = (const float*)d_in[1];
  const float* emb    = (const float*)d_in[2];
  const float* out_b  = (const float*)d_in[3];
  const float* h2eW   = (const float*)d_in[4];
  const float* h2eb   = (const float*)d_in[5];
  const float* Wih    = (const float*)d_in[6];
  const float* Whh    = (const float*)d_in[7];
  const float* bih    = (const float*)d_in[8];
  const float* bhh    = (const float*)d_in[9];

  char* ws8 = (char*)d_ws;
  ull*    SA   = (ull*)ws8;                              // [0, 32K)
  ull*    SB   = (ull*)(ws8 + 32768);                    // [32K, 64K)
  int*    done = (int*)(ws8 + 65536);                    // [64K, +1K)
  float*  Psum = (float*)(ws8 + 66560);                  // 4 KiB
  float*  Ttgt = (float*)(ws8 + 70656);                  // 4 KiB
  float*  X    = (float*)(ws8 + 81920);                  // 4 MiB
  char*   GIb  = ws8 + 81920 + (4u << 20);               // 24 MiB region
  double* GI   = (double*)GIb;
  double* E    = GI;                                     // 8 MiB overlay
  float*  candL = (float*)(GIb + (8u << 20));            // 3.06 MiB
  int*    candI = (int*)  (GIb + (8u << 20) + 3211264);  // 3.06 MiB
  double* H    = (double*)(ws8 + 81920 + (28u << 20));   // 8 MiB
  float*  out  = (float*)d_out;

  hipMemsetAsync(ws8, 0, 81920, stream);   // SA + SB + done + Psum + Ttgt

  k_gather<<<1024, 256, 0, stream>>>(inputs, emb, X);
  k_gemm_ffd<<<dim3(48, 16), 256, 0, stream>>>(X, Wih, bih, GI, 3072, KDIM);
  k_recur<<<64, 512, 0, stream>>>(z, Whh, bhh, GI, H, SA, SB, done);
  k_gemm_dfd<<<dim3(16, 16), 256, 0, stream>>>(H, h2eW, h2eb, E, KDIM, KDIM);
  k_logits<<<dim3(NCH, 16), 256, 0, stream>>>(E, emb, out_b, inputs,
                                              candL, candI, Psum, Ttgt);
  k_preds<<<T_STEPS, 256, 0, stream>>>(candL, candI, out);
  k_finish<<<1, 1024, 0, stream>>>(Psum, Ttgt, out);
}